// Round 2
// baseline (1753.137 us; speedup 1.0000x reference)
//
#include <hip/hip_runtime.h>
#include <cstdint>

// NeuralMemory forward. fp32 compute, bf16 storage for big intermediates.
// Shapes (fixed): B=4 T=8192 DIM=512 H=8 D=64 C=64 N=128 BH=32
// Workspace budget: ~130.5 MB (4 x 32MB bf16 + ~2.3MB fp32 small arrays).
#define EPS     1.1920929e-07f
#define MAX_LR  0.01f
#define BB      4
#define TT      8192
#define DIMM    512
#define HH      8
#define DD      64
#define CC      64
#define NN      128
#define BHH     32

__device__ __forceinline__ float sigmoidf_(float x){ return 1.0f/(1.0f+__expf(-x)); }
__device__ __forceinline__ float bf2f(uint32_t lo16){ return __uint_as_float(lo16<<16); }
__device__ __forceinline__ uint16_t f2bf(float f){
    uint32_t x = __float_as_uint(f);
    return (uint16_t)((x + 0x7fffu + ((x>>16)&1u)) >> 16);   // RNE
}

// ---------------------------------------------------------------------------
// K1: row scales of rmsnorm(seq); lr[bh][t]; gate[bh][j=t-63]
// one block (512 thr) per (b,t) row
// ---------------------------------------------------------------------------
__global__ __launch_bounds__(512) void k_norm_scale(
    const float* __restrict__ seq, const float* __restrict__ Wstep,
    const float* __restrict__ Wgate, float* __restrict__ scale,
    float* __restrict__ lr, float* __restrict__ gate)
{
    int row = blockIdx.x;              // b*T + t
    int tid = threadIdx.x;
    float x = seq[(size_t)row*DIMM + tid];
    float ss = x*x;
    #pragma unroll
    for (int o=32;o;o>>=1) ss += __shfl_down(ss,o,64);
    __shared__ float red[8];
    __shared__ float scale_sh;
    __shared__ float srow[DIMM];
    int wid = tid>>6, lane = tid&63;
    if (lane==0) red[wid]=ss;
    __syncthreads();
    if (tid==0){
        float tot=0.f;
        #pragma unroll
        for (int i=0;i<8;i++) tot+=red[i];
        float sc = rsqrtf(tot*(1.0f/DIMM)+EPS);
        scale_sh = sc;
        scale[row] = sc;
    }
    __syncthreads();
    srow[tid] = x*scale_sh;
    __syncthreads();
    // wave `wid` handles head `wid`
    float d1=0.f, d2=0.f;
    #pragma unroll
    for (int i=0;i<8;i++){
        int idx = i*64+lane;
        float svv = srow[idx];
        d1 += svv*Wstep[idx*HH+wid];
        d2 += svv*Wgate[idx*HH+wid];
    }
    #pragma unroll
    for (int o=32;o;o>>=1){ d1+=__shfl_down(d1,o,64); d2+=__shfl_down(d2,o,64); }
    if (lane==0){
        int b = row>>13, t = row&8191;
        lr[((size_t)(b*HH+wid))*TT + t] = sigmoidf_(d1)*MAX_LR;
        int j = t-63;
        if (j>=0) gate[((size_t)(b*HH+wid))*TT + j] = sigmoidf_(d2);
    }
}

// ---------------------------------------------------------------------------
// K2: chunk means of s=seq*scale -> mom_gate[bh][n], decay[bh][n]
// ---------------------------------------------------------------------------
__global__ __launch_bounds__(512) void k_chunk_gates(
    const float* __restrict__ seq, const float* __restrict__ scale,
    const float* __restrict__ Wmom, const float* __restrict__ Wdecay,
    float* __restrict__ mom, float* __restrict__ dec)
{
    int blk = blockIdx.x;              // b*N + n
    int b = blk>>7, n = blk&127;
    int tid = threadIdx.x;
    __shared__ float scl[CC];
    if (tid < CC) scl[tid] = scale[b*TT + n*CC + tid];
    __syncthreads();
    size_t base = ((size_t)b*TT + n*CC)*DIMM + tid;
    float acc=0.f;
    #pragma unroll 8
    for (int j=0;j<CC;j++) acc += seq[base + (size_t)j*DIMM]*scl[j];
    __shared__ float sm[DIMM];
    sm[tid] = acc*(1.0f/CC);
    __syncthreads();
    int wid = tid>>6, lane = tid&63;
    float d1=0.f, d2=0.f;
    #pragma unroll
    for (int i=0;i<8;i++){
        int idx=i*64+lane; float sv=sm[idx];
        d1 += sv*Wmom[idx*HH+wid];
        d2 += sv*Wdecay[idx*HH+wid];
    }
    #pragma unroll
    for (int o=32;o;o>>=1){ d1+=__shfl_down(d1,o,64); d2+=__shfl_down(d2,o,64); }
    if (lane==0){
        mom[(b*HH+wid)*NN + n] = sigmoidf_(d1);
        dec[(b*HH+wid)*NN + n] = sigmoidf_(d2);
    }
}

// ---------------------------------------------------------------------------
// Big GEMM: A(M x 512) @ Bm(512 x Ncols). 128x128 tile, 256 thr, 8x8/thr.
// MODE 0: A=seq*scale (f32); scatter bf16 cols into k (e<512) / v (e>=512)
// MODE 1: A=seq*scale (f32); row shift t->j=t-63, bf16 q head-split (skip j<0)
// MODE 2: A=y (bf16); row shift j->t'=j+63, f32 d_out rows (skip t'>=8192)
// ---------------------------------------------------------------------------
template<int MODE>
__global__ __launch_bounds__(256) void k_gemm(
    const void* __restrict__ Av, const float* __restrict__ Bm,
    const float* __restrict__ scale,
    void* __restrict__ out0, void* __restrict__ out1, int Ncols)
{
    __shared__ float As[16][128];
    __shared__ float Bs[16][128];
    int tid = threadIdx.x;
    int tx = tid & 15, ty = tid >> 4;
    int n0 = blockIdx.x * 128, m0 = blockIdx.y * 128;
    float acc[8][8];
    #pragma unroll
    for (int r=0;r<8;r++)
        #pragma unroll
        for (int c=0;c<8;c++) acc[r][c]=0.f;

    int ar = tid>>1;            // 0..127 row of A tile (2 threads/row)
    int ak = (tid&1)*8;         // 0 or 8
    int bk = tid>>4;            // 0..15 row of B tile
    int bn = (tid&15)*8;
    float sc = (MODE==2) ? 1.0f : scale[m0+ar];

    for (int k0=0;k0<DIMM;k0+=16){
        float a[8];
        if (MODE==2){
            const uint16_t* A = (const uint16_t*)Av;
            uint4 av = *(const uint4*)&A[(size_t)(m0+ar)*DIMM + k0 + ak];
            a[0]=bf2f(av.x&0xffffu); a[1]=bf2f(av.x>>16);
            a[2]=bf2f(av.y&0xffffu); a[3]=bf2f(av.y>>16);
            a[4]=bf2f(av.z&0xffffu); a[5]=bf2f(av.z>>16);
            a[6]=bf2f(av.w&0xffffu); a[7]=bf2f(av.w>>16);
        } else {
            const float* A = (const float*)Av;
            const float4* ap = (const float4*)&A[(size_t)(m0+ar)*DIMM + k0 + ak];
            float4 a0 = ap[0], a1 = ap[1];
            a[0]=a0.x*sc; a[1]=a0.y*sc; a[2]=a0.z*sc; a[3]=a0.w*sc;
            a[4]=a1.x*sc; a[5]=a1.y*sc; a[6]=a1.z*sc; a[7]=a1.w*sc;
        }
        const float4* bp = (const float4*)&Bm[(size_t)(k0+bk)*Ncols + n0 + bn];
        float4 b0 = bp[0], b1 = bp[1];
        #pragma unroll
        for (int i=0;i<8;i++) As[ak+i][ar]=a[i];
        *(float4*)&Bs[bk][bn]   = b0;
        *(float4*)&Bs[bk][bn+4] = b1;
        __syncthreads();
        #pragma unroll
        for (int kk=0;kk<16;kk++){
            float av[8], bv[8];
            *(float4*)&av[0] = *(const float4*)&As[kk][ty*8];
            *(float4*)&av[4] = *(const float4*)&As[kk][ty*8+4];
            *(float4*)&bv[0] = *(const float4*)&Bs[kk][tx*8];
            *(float4*)&bv[4] = *(const float4*)&Bs[kk][tx*8+4];
            #pragma unroll
            for (int r=0;r<8;r++)
                #pragma unroll
                for (int c=0;c<8;c++) acc[r][c] += av[r]*bv[c];
        }
        __syncthreads();
    }

    #pragma unroll
    for (int r=0;r<8;r++){
        int m = m0 + ty*8 + r;
        int b = m>>13, t = m&8191;
        if (MODE==0 || MODE==1){
            uint4 o;
            o.x = (uint32_t)f2bf(acc[r][0]) | ((uint32_t)f2bf(acc[r][1])<<16);
            o.y = (uint32_t)f2bf(acc[r][2]) | ((uint32_t)f2bf(acc[r][3])<<16);
            o.z = (uint32_t)f2bf(acc[r][4]) | ((uint32_t)f2bf(acc[r][5])<<16);
            o.w = (uint32_t)f2bf(acc[r][6]) | ((uint32_t)f2bf(acc[r][7])<<16);
            if (MODE==0){
                int e0 = n0 + tx*8;
                uint16_t* basep = (uint16_t*)((e0<512) ? out0 : out1);
                int ee = (e0<512) ? e0 : e0-512;
                int h = ee>>6, dk = ee&63;
                *(uint4*)(basep + (((size_t)(b*HH+h)*TT + t)*DD + dk)) = o;
            } else {
                int j = t-63;
                if (j>=0){
                    int e0 = n0 + tx*8;
                    int h = e0>>6, dk = e0&63;
                    *(uint4*)((uint16_t*)out0 + (((size_t)(b*HH+h)*TT + j)*DD + dk)) = o;
                }
            }
        } else {
            int tp = t + 63;
            if (tp < TT){
                float* dst = (float*)out0 + ((size_t)b*TT + tp)*DIMM + n0 + tx*8;
                *(float4*)dst = make_float4(acc[r][0],acc[r][1],acc[r][2],acc[r][3]);
                *(float4*)(dst+4) = make_float4(acc[r][4],acc[r][5],acc[r][6],acc[r][7]);
            }
        }
    }
}

// ---------------------------------------------------------------------------
// K4: per-chunk MLP gradient. One block per (bh,n). 64KB LDS, 4x4/thread.
// k/v bf16 in; surprises -g1,-g2 bf16 out at [(bh*N+n)*4096 + p*64+q]
// ---------------------------------------------------------------------------
__global__ __launch_bounds__(256) void k_grad(
    const uint16_t* __restrict__ kbuf, const uint16_t* __restrict__ vbuf,
    const float* __restrict__ lr, const float* __restrict__ w1,
    const float* __restrict__ w2, uint16_t* __restrict__ g1, uint16_t* __restrict__ g2)
{
    __shared__ float kc[64][64];
    __shared__ float hs[64][64];
    __shared__ float dx2s[64][64];
    __shared__ float wb[64][64];
    int bhn = blockIdx.x;
    int bh = bhn>>7, n = bhn&127;
    int tid = threadIdx.x, tx = tid&15, ty = tid>>4;
    size_t cbase = ((size_t)bh*TT + n*CC)*DD;

    #pragma unroll
    for (int r=0;r<4;r++){
        int row = ty*4+r;
        ushort4 k4 = *(const ushort4*)&kbuf[cbase + row*DD + tx*4];
        kc[row][tx*4+0]=bf2f(k4.x); kc[row][tx*4+1]=bf2f(k4.y);
        kc[row][tx*4+2]=bf2f(k4.z); kc[row][tx*4+3]=bf2f(k4.w);
        *(float4*)&wb[row][tx*4] = *(const float4*)&w1[row*DD + tx*4];
    }
    __syncthreads();

    // GEMM1: x1 = kc @ w1 ; silu
    float accA[4][4] = {};
    for (int k=0;k<64;k++){
        float a[4], bv[4];
        #pragma unroll
        for (int r=0;r<4;r++) a[r]=kc[ty*4+r][k];
        *(float4*)bv = *(const float4*)&wb[k][tx*4];
        #pragma unroll
        for (int r=0;r<4;r++)
            #pragma unroll
            for (int c=0;c<4;c++) accA[r][c] += a[r]*bv[c];
    }
    float sg[4][4], hr[4][4];
    #pragma unroll
    for (int r=0;r<4;r++)
        #pragma unroll
        for (int c=0;c<4;c++){
            float x = accA[r][c];
            float sgm = sigmoidf_(x);
            sg[r][c]=sgm; hr[r][c]=x*sgm;
            hs[ty*4+r][tx*4+c] = x*sgm;
        }
    __syncthreads();
    #pragma unroll
    for (int r=0;r<4;r++)
        *(float4*)&wb[ty*4+r][tx*4] = *(const float4*)&w2[(ty*4+r)*DD + tx*4];
    __syncthreads();

    // GEMM2: x2 = h @ w2 ; dx2 = (2/D)*lr_row*(x2 - v)
    float acc2[4][4] = {};
    for (int k=0;k<64;k++){
        float a[4], bv[4];
        #pragma unroll
        for (int r=0;r<4;r++) a[r]=hs[ty*4+r][k];
        *(float4*)bv = *(const float4*)&wb[k][tx*4];
        #pragma unroll
        for (int r=0;r<4;r++)
            #pragma unroll
            for (int c=0;c<4;c++) acc2[r][c] += a[r]*bv[c];
    }
    #pragma unroll
    for (int r=0;r<4;r++){
        int row = ty*4+r;
        float lrv = lr[(size_t)bh*TT + n*CC + row];
        ushort4 v4 = *(const ushort4*)&vbuf[cbase + row*DD + tx*4];
        float vz[4] = {bf2f(v4.x),bf2f(v4.y),bf2f(v4.z),bf2f(v4.w)};
        #pragma unroll
        for (int c=0;c<4;c++)
            dx2s[row][tx*4+c] = (2.0f/DD)*lrv*(acc2[r][c]-vz[c]);
    }
    __syncthreads();

    // GEMM3: g2 = h^T @ dx2  (write -g2 bf16)
    float acc3[4][4] = {};
    for (int i=0;i<64;i++){
        float a[4], bv[4];
        #pragma unroll
        for (int r=0;r<4;r++) a[r]=hs[i][ty*4+r];
        *(float4*)bv = *(const float4*)&dx2s[i][tx*4];
        #pragma unroll
        for (int r=0;r<4;r++)
            #pragma unroll
            for (int c=0;c<4;c++) acc3[r][c] += a[r]*bv[c];
    }
    size_t gbase = (size_t)bhn*4096;
    #pragma unroll
    for (int r=0;r<4;r++){
        ushort4 o;
        o.x=f2bf(-acc3[r][0]); o.y=f2bf(-acc3[r][1]);
        o.z=f2bf(-acc3[r][2]); o.w=f2bf(-acc3[r][3]);
        *(ushort4*)&g2[gbase + (ty*4+r)*DD + tx*4] = o;
    }
    __syncthreads();   // all hs reads done before overwrite with dx1

    // GEMM4: dh = dx2 @ w2^T ; dx1 = dh*silu'(x1) -> hs
    float acc4[4][4] = {};
    for (int q=0;q<64;q++){
        float a[4], bv[4];
        #pragma unroll
        for (int r=0;r<4;r++) a[r]=dx2s[ty*4+r][q];
        #pragma unroll
        for (int c=0;c<4;c++) bv[c]=wb[tx*4+c][q];
        #pragma unroll
        for (int r=0;r<4;r++)
            #pragma unroll
            for (int c=0;c<4;c++) acc4[r][c] += a[r]*bv[c];
    }
    #pragma unroll
    for (int r=0;r<4;r++)
        #pragma unroll
        for (int c=0;c<4;c++){
            float dsilu = sg[r][c] + hr[r][c]*(1.f-sg[r][c]);
            hs[ty*4+r][tx*4+c] = acc4[r][c]*dsilu;
        }
    __syncthreads();

    // GEMM5: g1 = kc^T @ dx1  (write -g1 bf16)
    float acc5[4][4] = {};
    for (int i=0;i<64;i++){
        float a[4], bv[4];
        #pragma unroll
        for (int r=0;r<4;r++) a[r]=kc[i][ty*4+r];
        *(float4*)bv = *(const float4*)&hs[i][tx*4];
        #pragma unroll
        for (int r=0;r<4;r++)
            #pragma unroll
            for (int c=0;c<4;c++) acc5[r][c] += a[r]*bv[c];
    }
    #pragma unroll
    for (int r=0;r<4;r++){
        ushort4 o;
        o.x=f2bf(-acc5[r][0]); o.y=f2bf(-acc5[r][1]);
        o.z=f2bf(-acc5[r][2]); o.w=f2bf(-acc5[r][3]);
        *(ushort4*)&g1[gbase + (ty*4+r)*DD + tx*4] = o;
    }
}

// ---------------------------------------------------------------------------
// K5: two stacked first-order scans over n=128, in place on bf16 g1/g2.
// state fp32 in registers; each thread owns 2 adjacent elements (uint rmw)
// ---------------------------------------------------------------------------
__global__ __launch_bounds__(256) void k_scan(
    uint16_t* __restrict__ g1, uint16_t* __restrict__ g2,
    const float* __restrict__ mom, const float* __restrict__ dec)
{
    int blk = blockIdx.x;            // [0,512)
    int arr = blk>>8; int rem = blk&255;
    int bh = rem>>3; int eg = rem&7;
    int e2 = eg*512 + threadIdx.x*2;
    uint16_t* gp = arr ? g2 : g1;
    __shared__ float smg[NN], sdc[NN];
    if (threadIdx.x < NN){
        smg[threadIdx.x] = mom[bh*NN+threadIdx.x];
        sdc[threadIdx.x] = 1.f - dec[bh*NN+threadIdx.x];
    }
    __syncthreads();
    size_t base = (size_t)bh*NN*4096 + e2;
    float ma=0.f, mb=0.f, ua=0.f, ub=0.f;
    for (int t=0;t<NN;t++){
        uint32_t w = *(const uint32_t*)&gp[base + (size_t)t*4096];
        float f0 = bf2f(w&0xffffu), f1 = bf2f(w>>16);
        float mg = smg[t], dc = sdc[t];
        ma = fmaf(mg,ma,f0); ua = fmaf(dc,ua,ma);
        mb = fmaf(mg,mb,f1); ub = fmaf(dc,ub,mb);
        *(uint32_t*)&gp[base + (size_t)t*4096] =
            (uint32_t)f2bf(ua) | ((uint32_t)f2bf(ub)<<16);
    }
}

// ---------------------------------------------------------------------------
// K6: retrieve. x=silu(qc@(w1+u1))@(w2+u2); rmsnorm(d=64)*(1+gamma)*gate -> y
// q,u1,u2 bf16 in; y bf16 merged layout y[b][j][h*64+dk]. One block per (bh,n).
// ---------------------------------------------------------------------------
__global__ __launch_bounds__(256) void k_retrieve(
    const uint16_t* __restrict__ qbuf, const uint16_t* __restrict__ u1,
    const uint16_t* __restrict__ u2, const float* __restrict__ w1,
    const float* __restrict__ w2, const float* __restrict__ gamma,
    const float* __restrict__ gate, uint16_t* __restrict__ y)
{
    __shared__ float qc[64][64];
    __shared__ float w1p[64][64];
    __shared__ float w2p[64][64];
    __shared__ float hsil[64][64];
    int bhn = blockIdx.x;
    int bh = bhn>>7, n = bhn&127;
    int b = bh>>3, h = bh&7;
    int tid = threadIdx.x, tx = tid&15, ty = tid>>4;
    size_t cbase = ((size_t)bh*TT + n*CC)*DD;
    size_t ub = (size_t)bhn*4096;

    #pragma unroll
    for (int r=0;r<4;r++){
        int row = ty*4+r;
        ushort4 q4 = *(const ushort4*)&qbuf[cbase + row*DD + tx*4];
        qc[row][tx*4+0]=bf2f(q4.x); qc[row][tx*4+1]=bf2f(q4.y);
        qc[row][tx*4+2]=bf2f(q4.z); qc[row][tx*4+3]=bf2f(q4.w);
        float4 wv1 = *(const float4*)&w1[row*DD+tx*4];
        ushort4 u14 = *(const ushort4*)&u1[ub + row*DD + tx*4];
        w1p[row][tx*4+0]=wv1.x+bf2f(u14.x); w1p[row][tx*4+1]=wv1.y+bf2f(u14.y);
        w1p[row][tx*4+2]=wv1.z+bf2f(u14.z); w1p[row][tx*4+3]=wv1.w+bf2f(u14.w);
        float4 wv2 = *(const float4*)&w2[row*DD+tx*4];
        ushort4 u24 = *(const ushort4*)&u2[ub + row*DD + tx*4];
        w2p[row][tx*4+0]=wv2.x+bf2f(u24.x); w2p[row][tx*4+1]=wv2.y+bf2f(u24.y);
        w2p[row][tx*4+2]=wv2.z+bf2f(u24.z); w2p[row][tx*4+3]=wv2.w+bf2f(u24.w);
    }
    __syncthreads();

    float accA[4][4] = {};
    for (int k=0;k<64;k++){
        float a[4], bv[4];
        #pragma unroll
        for (int r=0;r<4;r++) a[r]=qc[ty*4+r][k];
        *(float4*)bv = *(const float4*)&w1p[k][tx*4];
        #pragma unroll
        for (int r=0;r<4;r++)
            #pragma unroll
            for (int c=0;c<4;c++) accA[r][c] += a[r]*bv[c];
    }
    #pragma unroll
    for (int r=0;r<4;r++)
        #pragma unroll
        for (int c=0;c<4;c++){
            float x = accA[r][c];
            hsil[ty*4+r][tx*4+c] = x*sigmoidf_(x);
        }
    __syncthreads();

    float accB[4][4] = {};
    for (int k=0;k<64;k++){
        float a[4], bv[4];
        #pragma unroll
        for (int r=0;r<4;r++) a[r]=hsil[ty*4+r][k];
        *(float4*)bv = *(const float4*)&w2p[k][tx*4];
        #pragma unroll
        for (int r=0;r<4;r++)
            #pragma unroll
            for (int c=0;c<4;c++) accB[r][c] += a[r]*bv[c];
    }
    // row sums of squares: partials into w1p[row][tx] (w1p no longer needed)
    #pragma unroll
    for (int r=0;r<4;r++){
        float p = accB[r][0]*accB[r][0]+accB[r][1]*accB[r][1]
                + accB[r][2]*accB[r][2]+accB[r][3]*accB[r][3];
        w1p[ty*4+r][tx] = p;
    }
    __syncthreads();
    #pragma unroll
    for (int r=0;r<4;r++){
        int row = ty*4+r;
        float rs=0.f;
        #pragma unroll
        for (int i=0;i<16;i++) rs += w1p[row][i];
        float sclv = rsqrtf(rs*(1.0f/DD)+EPS);
        float gt = gate[(size_t)bh*TT + n*CC + row];
        float4 gm = *(const float4*)&gamma[h*DD + tx*4];
        ushort4 o;
        o.x = f2bf(accB[r][0]*sclv*(1.f+gm.x)*gt);
        o.y = f2bf(accB[r][1]*sclv*(1.f+gm.y)*gt);
        o.z = f2bf(accB[r][2]*sclv*(1.f+gm.z)*gt);
        o.w = f2bf(accB[r][3]*sclv*(1.f+gm.w)*gt);
        *(ushort4*)&y[((size_t)b*TT + n*CC + row)*DIMM + h*DD + tx*4] = o;
    }
}

// ---------------------------------------------------------------------------
// K7: zero pads — q rows j in [8129,8191] (bf16, all bh); out rows [0,62] (f32)
// ---------------------------------------------------------------------------
__global__ __launch_bounds__(256) void k_zero(uint16_t* __restrict__ qbuf, float* __restrict__ out)
{
    int g = blockIdx.x*256 + threadIdx.x;
    const int QN = BHH*63*DD;          // 129024
    if (g < QN){
        int bh = g/4032; int r = g - bh*4032;
        int j = 8129 + (r>>6); int dk = r&63;
        qbuf[((size_t)bh*TT + j)*DD + dk] = 0;
    } else {
        int g2i = g - QN;              // < 4*63*512 = 129024
        int b = g2i/(63*512); int r = g2i - b*63*512;
        int t = r>>9; int e = r&511;
        out[((size_t)b*TT + t)*DIMM + e] = 0.f;
    }
}

// ---------------------------------------------------------------------------
extern "C" void kernel_launch(void* const* d_in, const int* in_sizes, int n_in,
                              void* d_out, int out_size, void* d_ws, size_t ws_size,
                              hipStream_t stream)
{
    (void)in_sizes; (void)n_in; (void)out_size; (void)ws_size;
    const float* seq    = (const float*)d_in[0];
    const float* w1     = (const float*)d_in[1];
    const float* w2     = (const float*)d_in[2];
    const float* Wq     = (const float*)d_in[3];
    const float* Wkv    = (const float*)d_in[4];
    const float* Wstep  = (const float*)d_in[5];
    const float* Wmom   = (const float*)d_in[6];
    const float* Wdecay = (const float*)d_in[7];
    const float* Wgate  = (const float*)d_in[8];
    const float* Wcomb  = (const float*)d_in[9];
    const float* gamma  = (const float*)d_in[10];
    float* out = (float*)d_out;

    // workspace layout: ~2.26MB fp32 small + 4 x 32MB bf16 = ~130.5MB
    float* scale = (float*)d_ws;          // 32768
    float* lr    = scale + 32768;         // 262144
    float* gate  = lr + 262144;           // 262144
    float* mom   = gate + 262144;         // 4096
    float* dec   = mom + 4096;            // 4096
    uint16_t* kb = (uint16_t*)(dec + 4096);  // 16777216 bf16 (q reuses after k_grad)
    uint16_t* vb = kb + 16777216;            // 16777216 bf16 (y reuses after k_retrieve)
    uint16_t* g1 = vb + 16777216;            // 16777216 bf16 (in-place scan -> upd1)
    uint16_t* g2 = g1 + 16777216;            // 16777216 bf16 (in-place scan -> upd2)

    k_norm_scale <<<BB*TT, 512, 0, stream>>>(seq, Wstep, Wgate, scale, lr, gate);
    k_chunk_gates<<<BB*NN, 512, 0, stream>>>(seq, scale, Wmom, Wdecay, mom, dec);
    k_gemm<0><<<dim3(8, 256), 256, 0, stream>>>(seq, Wkv, scale, kb, vb, 1024);
    k_grad   <<<BHH*NN, 256, 0, stream>>>(kb, vb, lr, w1, w2, g1, g2);
    k_scan   <<<512, 256, 0, stream>>>(g1, g2, mom, dec);
    k_gemm<1><<<dim3(4, 256), 256, 0, stream>>>(seq, Wq, scale, kb /*q*/, nullptr, 512);
    k_zero   <<<1008, 256, 0, stream>>>(kb /*q*/, out);
    k_retrieve<<<BHH*NN, 256, 0, stream>>>(kb /*q*/, g1, g2, w1, w2, gamma, gate, vb /*y*/);
    k_gemm<2><<<dim3(4, 256), 256, 0, stream>>>(vb /*y*/, Wcomb, scale, out, nullptr, 512);
}

// Round 3
// 1354.136 us; speedup vs baseline: 1.2947x; 1.2947x over previous
//
#include <hip/hip_runtime.h>
#include <cstdint>

// NeuralMemory forward. fp32 compute, bf16 storage for big intermediates.
// Shapes (fixed): B=4 T=8192 DIM=512 H=8 D=64 C=64 N=128 BH=32
// Workspace ~130.5 MB. lr/gate stored transposed: [b][t][h] (coalesced writes).
#define EPS     1.1920929e-07f
#define MAX_LR  0.01f
#define BB      4
#define TT      8192
#define DIMM    512
#define HH      8
#define DD      64
#define CC      64
#define NN      128
#define BHH     32

__device__ __forceinline__ float sigmoidf_(float x){ return 1.0f/(1.0f+__expf(-x)); }
__device__ __forceinline__ float bf2f(uint32_t lo16){ return __uint_as_float(lo16<<16); }
__device__ __forceinline__ uint16_t f2bf(float f){
    uint32_t x = __float_as_uint(f);
    return (uint16_t)((x + 0x7fffu + ((x>>16)&1u)) >> 16);   // RNE
}

// ---------------------------------------------------------------------------
// K1: wave-per-row rmsnorm scale + lr/gate head-dots.
// 8192 blocks x 256 thr (4 waves); wave w handles row = blk*4+w.
// lr_t[b][t][h], gate_t[b][j][h] (j=t-63), scale[row].
// ---------------------------------------------------------------------------
__global__ __launch_bounds__(256) void k_norm_scale(
    const float* __restrict__ seq, const float* __restrict__ Wstep,
    const float* __restrict__ Wgate, float* __restrict__ scale,
    float* __restrict__ lr_t, float* __restrict__ gate_t)
{
    int wave = threadIdx.x >> 6, lane = threadIdx.x & 63;
    int row = blockIdx.x*4 + wave;          // b*T + t
    const float4* sp = (const float4*)&seq[(size_t)row*DIMM + lane*8];
    float4 x0 = sp[0], x1 = sp[1];
    float xs[8] = {x0.x,x0.y,x0.z,x0.w,x1.x,x1.y,x1.z,x1.w};
    float ss = 0.f;
    #pragma unroll
    for (int i=0;i<8;i++) ss += xs[i]*xs[i];
    #pragma unroll
    for (int o=32;o;o>>=1) ss += __shfl_xor(ss,o,64);
    float sc = rsqrtf(ss*(1.0f/DIMM)+EPS);
    if (lane==0) scale[row]=sc;

    float d1[8]={0,0,0,0,0,0,0,0}, d2[8]={0,0,0,0,0,0,0,0};
    int idx0 = lane*8;
    #pragma unroll
    for (int i=0;i<8;i++){
        float sv = xs[i]*sc;
        float4 wa = *(const float4*)&Wstep[(idx0+i)*HH];
        float4 wb4= *(const float4*)&Wstep[(idx0+i)*HH+4];
        d1[0]+=sv*wa.x;  d1[1]+=sv*wa.y;  d1[2]+=sv*wa.z;  d1[3]+=sv*wa.w;
        d1[4]+=sv*wb4.x; d1[5]+=sv*wb4.y; d1[6]+=sv*wb4.z; d1[7]+=sv*wb4.w;
        float4 ga = *(const float4*)&Wgate[(idx0+i)*HH];
        float4 gb = *(const float4*)&Wgate[(idx0+i)*HH+4];
        d2[0]+=sv*ga.x; d2[1]+=sv*ga.y; d2[2]+=sv*ga.z; d2[3]+=sv*ga.w;
        d2[4]+=sv*gb.x; d2[5]+=sv*gb.y; d2[6]+=sv*gb.z; d2[7]+=sv*gb.w;
    }
    #pragma unroll
    for (int o=32;o;o>>=1){
        #pragma unroll
        for (int h=0;h<8;h++){
            d1[h]+=__shfl_down(d1[h],o,64);
            d2[h]+=__shfl_down(d2[h],o,64);
        }
    }
    if (lane==0){
        int b = row>>13, t = row&8191;
        float4 l0 = make_float4(sigmoidf_(d1[0])*MAX_LR, sigmoidf_(d1[1])*MAX_LR,
                                sigmoidf_(d1[2])*MAX_LR, sigmoidf_(d1[3])*MAX_LR);
        float4 l1 = make_float4(sigmoidf_(d1[4])*MAX_LR, sigmoidf_(d1[5])*MAX_LR,
                                sigmoidf_(d1[6])*MAX_LR, sigmoidf_(d1[7])*MAX_LR);
        *(float4*)&lr_t[(size_t)row*HH]   = l0;
        *(float4*)&lr_t[(size_t)row*HH+4] = l1;
        int j = t-63;
        if (j>=0){
            size_t go = ((size_t)b*TT + j)*HH;
            float4 g0 = make_float4(sigmoidf_(d2[0]), sigmoidf_(d2[1]),
                                    sigmoidf_(d2[2]), sigmoidf_(d2[3]));
            float4 g1v= make_float4(sigmoidf_(d2[4]), sigmoidf_(d2[5]),
                                    sigmoidf_(d2[6]), sigmoidf_(d2[7]));
            *(float4*)&gate_t[go]   = g0;
            *(float4*)&gate_t[go+4] = g1v;
        }
    }
}

// ---------------------------------------------------------------------------
// K2: chunk means of s=seq*scale -> mom_gate[bh][n], decay[bh][n]
// ---------------------------------------------------------------------------
__global__ __launch_bounds__(512) void k_chunk_gates(
    const float* __restrict__ seq, const float* __restrict__ scale,
    const float* __restrict__ Wmom, const float* __restrict__ Wdecay,
    float* __restrict__ mom, float* __restrict__ dec)
{
    int blk = blockIdx.x;              // b*N + n
    int b = blk>>7, n = blk&127;
    int tid = threadIdx.x;
    __shared__ float scl[CC];
    if (tid < CC) scl[tid] = scale[b*TT + n*CC + tid];
    __syncthreads();
    size_t base = ((size_t)b*TT + n*CC)*DIMM + tid;
    float acc=0.f;
    #pragma unroll 8
    for (int j=0;j<CC;j++) acc += seq[base + (size_t)j*DIMM]*scl[j];
    __shared__ float sm[DIMM];
    sm[tid] = acc*(1.0f/CC);
    __syncthreads();
    int wid = tid>>6, lane = tid&63;
    float d1=0.f, d2=0.f;
    #pragma unroll
    for (int i=0;i<8;i++){
        int idx=i*64+lane; float sv=sm[idx];
        d1 += sv*Wmom[idx*HH+wid];
        d2 += sv*Wdecay[idx*HH+wid];
    }
    #pragma unroll
    for (int o=32;o;o>>=1){ d1+=__shfl_down(d1,o,64); d2+=__shfl_down(d2,o,64); }
    if (lane==0){
        mom[(b*HH+wid)*NN + n] = sigmoidf_(d1);
        dec[(b*HH+wid)*NN + n] = sigmoidf_(d2);
    }
}

// ---------------------------------------------------------------------------
// Big GEMM: A(M x 512) @ Bm(512 x Ncols). 128x128 tile, 256 thr, 8x8/thr.
// MODE 0: A=seq*scale (f32); scatter bf16 cols into k (e<512) / v (e>=512)
// MODE 1: A=seq*scale (f32); row shift t->j=t-63, bf16 q head-split (skip j<0)
// MODE 2: A=y (bf16); row shift j->t'=j+63, f32 d_out rows (skip t'>=8192)
// ---------------------------------------------------------------------------
template<int MODE>
__global__ __launch_bounds__(256) void k_gemm(
    const void* __restrict__ Av, const float* __restrict__ Bm,
    const float* __restrict__ scale,
    void* __restrict__ out0, void* __restrict__ out1, int Ncols)
{
    __shared__ float As[16][128];
    __shared__ float Bs[16][128];
    int tid = threadIdx.x;
    int tx = tid & 15, ty = tid >> 4;
    int n0 = blockIdx.x * 128, m0 = blockIdx.y * 128;
    float acc[8][8];
    #pragma unroll
    for (int r=0;r<8;r++)
        #pragma unroll
        for (int c=0;c<8;c++) acc[r][c]=0.f;

    int ar = tid>>1;            // 0..127 row of A tile (2 threads/row)
    int ak = (tid&1)*8;         // 0 or 8
    int bk = tid>>4;            // 0..15 row of B tile
    int bn = (tid&15)*8;
    float sc = (MODE==2) ? 1.0f : scale[m0+ar];

    for (int k0=0;k0<DIMM;k0+=16){
        float a[8];
        if (MODE==2){
            const uint16_t* A = (const uint16_t*)Av;
            uint4 av = *(const uint4*)&A[(size_t)(m0+ar)*DIMM + k0 + ak];
            a[0]=bf2f(av.x&0xffffu); a[1]=bf2f(av.x>>16);
            a[2]=bf2f(av.y&0xffffu); a[3]=bf2f(av.y>>16);
            a[4]=bf2f(av.z&0xffffu); a[5]=bf2f(av.z>>16);
            a[6]=bf2f(av.w&0xffffu); a[7]=bf2f(av.w>>16);
        } else {
            const float* A = (const float*)Av;
            const float4* ap = (const float4*)&A[(size_t)(m0+ar)*DIMM + k0 + ak];
            float4 a0 = ap[0], a1 = ap[1];
            a[0]=a0.x*sc; a[1]=a0.y*sc; a[2]=a0.z*sc; a[3]=a0.w*sc;
            a[4]=a1.x*sc; a[5]=a1.y*sc; a[6]=a1.z*sc; a[7]=a1.w*sc;
        }
        const float4* bp = (const float4*)&Bm[(size_t)(k0+bk)*Ncols + n0 + bn];
        float4 b0 = bp[0], b1 = bp[1];
        #pragma unroll
        for (int i=0;i<8;i++) As[ak+i][ar]=a[i];
        *(float4*)&Bs[bk][bn]   = b0;
        *(float4*)&Bs[bk][bn+4] = b1;
        __syncthreads();
        #pragma unroll
        for (int kk=0;kk<16;kk++){
            float av[8], bv[8];
            *(float4*)&av[0] = *(const float4*)&As[kk][ty*8];
            *(float4*)&av[4] = *(const float4*)&As[kk][ty*8+4];
            *(float4*)&bv[0] = *(const float4*)&Bs[kk][tx*8];
            *(float4*)&bv[4] = *(const float4*)&Bs[kk][tx*8+4];
            #pragma unroll
            for (int r=0;r<8;r++)
                #pragma unroll
                for (int c=0;c<8;c++) acc[r][c] += av[r]*bv[c];
        }
        __syncthreads();
    }

    #pragma unroll
    for (int r=0;r<8;r++){
        int m = m0 + ty*8 + r;
        int b = m>>13, t = m&8191;
        if (MODE==0 || MODE==1){
            uint4 o;
            o.x = (uint32_t)f2bf(acc[r][0]) | ((uint32_t)f2bf(acc[r][1])<<16);
            o.y = (uint32_t)f2bf(acc[r][2]) | ((uint32_t)f2bf(acc[r][3])<<16);
            o.z = (uint32_t)f2bf(acc[r][4]) | ((uint32_t)f2bf(acc[r][5])<<16);
            o.w = (uint32_t)f2bf(acc[r][6]) | ((uint32_t)f2bf(acc[r][7])<<16);
            if (MODE==0){
                int e0 = n0 + tx*8;
                uint16_t* basep = (uint16_t*)((e0<512) ? out0 : out1);
                int ee = (e0<512) ? e0 : e0-512;
                int h = ee>>6, dk = ee&63;
                *(uint4*)(basep + (((size_t)(b*HH+h)*TT + t)*DD + dk)) = o;
            } else {
                int j = t-63;
                if (j>=0){
                    int e0 = n0 + tx*8;
                    int h = e0>>6, dk = e0&63;
                    *(uint4*)((uint16_t*)out0 + (((size_t)(b*HH+h)*TT + j)*DD + dk)) = o;
                }
            }
        } else {
            int tp = t + 63;
            if (tp < TT){
                float* dst = (float*)out0 + ((size_t)b*TT + tp)*DIMM + n0 + tx*8;
                *(float4*)dst = make_float4(acc[r][0],acc[r][1],acc[r][2],acc[r][3]);
                *(float4*)(dst+4) = make_float4(acc[r][4],acc[r][5],acc[r][6],acc[r][7]);
            }
        }
    }
}

// ---------------------------------------------------------------------------
// K4: per-chunk MLP gradient. One block per (bh,n). ~81KB LDS, 4x4/thread.
// k/v bf16 in; surprises -g1,-g2 bf16 out at [(bh*N+n)*4096 + p*64+q]
// lr_t layout [b][t][h].
// ---------------------------------------------------------------------------
__global__ __launch_bounds__(256) void k_grad(
    const uint16_t* __restrict__ kbuf, const uint16_t* __restrict__ vbuf,
    const float* __restrict__ lr_t, const float* __restrict__ w1,
    const float* __restrict__ w2, uint16_t* __restrict__ g1, uint16_t* __restrict__ g2)
{
    __shared__ float kc[64][64];
    __shared__ float hs[64][64];
    __shared__ float dx2s[64][64];
    __shared__ float wb[64][64];
    __shared__ float wbT[64][68];   // wbT[q][j] = w2[j][q]; 68 keeps float4 align + bank spread
    int bhn = blockIdx.x;
    int bh = bhn>>7, n = bhn&127;
    int b = bh>>3, h = bh&7;
    int tid = threadIdx.x, tx = tid&15, ty = tid>>4;
    size_t cbase = ((size_t)bh*TT + n*CC)*DD;

    #pragma unroll
    for (int r=0;r<4;r++){
        int row = ty*4+r;
        ushort4 k4 = *(const ushort4*)&kbuf[cbase + row*DD + tx*4];
        kc[row][tx*4+0]=bf2f(k4.x); kc[row][tx*4+1]=bf2f(k4.y);
        kc[row][tx*4+2]=bf2f(k4.z); kc[row][tx*4+3]=bf2f(k4.w);
        *(float4*)&wb[row][tx*4] = *(const float4*)&w1[row*DD + tx*4];
    }
    __syncthreads();

    // GEMM1: x1 = kc @ w1 ; silu
    float accA[4][4] = {};
    for (int k=0;k<64;k++){
        float a[4], bv[4];
        #pragma unroll
        for (int r=0;r<4;r++) a[r]=kc[ty*4+r][k];
        *(float4*)bv = *(const float4*)&wb[k][tx*4];
        #pragma unroll
        for (int r=0;r<4;r++)
            #pragma unroll
            for (int c=0;c<4;c++) accA[r][c] += a[r]*bv[c];
    }
    float sg[4][4], hr[4][4];
    #pragma unroll
    for (int r=0;r<4;r++)
        #pragma unroll
        for (int c=0;c<4;c++){
            float x = accA[r][c];
            float sgm = sigmoidf_(x);
            sg[r][c]=sgm; hr[r][c]=x*sgm;
            hs[ty*4+r][tx*4+c] = x*sgm;
        }
    __syncthreads();
    #pragma unroll
    for (int r=0;r<4;r++){
        int row = ty*4+r;
        float4 wv = *(const float4*)&w2[row*DD + tx*4];
        *(float4*)&wb[row][tx*4] = wv;
        wbT[tx*4+0][row]=wv.x; wbT[tx*4+1][row]=wv.y;
        wbT[tx*4+2][row]=wv.z; wbT[tx*4+3][row]=wv.w;
    }
    __syncthreads();

    // GEMM2: x2 = h @ w2 ; dx2 = (2/D)*lr_row*(x2 - v)
    float acc2[4][4] = {};
    for (int k=0;k<64;k++){
        float a[4], bv[4];
        #pragma unroll
        for (int r=0;r<4;r++) a[r]=hs[ty*4+r][k];
        *(float4*)bv = *(const float4*)&wb[k][tx*4];
        #pragma unroll
        for (int r=0;r<4;r++)
            #pragma unroll
            for (int c=0;c<4;c++) acc2[r][c] += a[r]*bv[c];
    }
    #pragma unroll
    for (int r=0;r<4;r++){
        int row = ty*4+r;
        float lrv = lr_t[((size_t)b*TT + n*CC + row)*HH + h];
        ushort4 v4 = *(const ushort4*)&vbuf[cbase + row*DD + tx*4];
        float vz[4] = {bf2f(v4.x),bf2f(v4.y),bf2f(v4.z),bf2f(v4.w)};
        #pragma unroll
        for (int c=0;c<4;c++)
            dx2s[row][tx*4+c] = (2.0f/DD)*lrv*(acc2[r][c]-vz[c]);
    }
    __syncthreads();

    // GEMM3: g2 = h^T @ dx2  (write -g2 bf16)
    float acc3[4][4] = {};
    for (int i=0;i<64;i++){
        float a[4], bv[4];
        #pragma unroll
        for (int r=0;r<4;r++) a[r]=hs[i][ty*4+r];
        *(float4*)bv = *(const float4*)&dx2s[i][tx*4];
        #pragma unroll
        for (int r=0;r<4;r++)
            #pragma unroll
            for (int c=0;c<4;c++) acc3[r][c] += a[r]*bv[c];
    }
    size_t gbase = (size_t)bhn*4096;
    #pragma unroll
    for (int r=0;r<4;r++){
        ushort4 o;
        o.x=f2bf(-acc3[r][0]); o.y=f2bf(-acc3[r][1]);
        o.z=f2bf(-acc3[r][2]); o.w=f2bf(-acc3[r][3]);
        *(ushort4*)&g2[gbase + (ty*4+r)*DD + tx*4] = o;
    }
    __syncthreads();   // all hs reads done before overwrite with dx1

    // GEMM4: dh = dx2 @ w2^T ; dx1 = dh*silu'(x1) -> hs
    float acc4[4][4] = {};
    for (int q=0;q<64;q++){
        float a[4], bv[4];
        #pragma unroll
        for (int r=0;r<4;r++) a[r]=dx2s[ty*4+r][q];
        *(float4*)bv = *(const float4*)&wbT[q][tx*4];
        #pragma unroll
        for (int r=0;r<4;r++)
            #pragma unroll
            for (int c=0;c<4;c++) acc4[r][c] += a[r]*bv[c];
    }
    #pragma unroll
    for (int r=0;r<4;r++)
        #pragma unroll
        for (int c=0;c<4;c++){
            float dsilu = sg[r][c] + hr[r][c]*(1.f-sg[r][c]);
            hs[ty*4+r][tx*4+c] = acc4[r][c]*dsilu;
        }
    __syncthreads();

    // GEMM5: g1 = kc^T @ dx1  (write -g1 bf16)
    float acc5[4][4] = {};
    for (int i=0;i<64;i++){
        float a[4], bv[4];
        #pragma unroll
        for (int r=0;r<4;r++) a[r]=kc[i][ty*4+r];
        *(float4*)bv = *(const float4*)&hs[i][tx*4];
        #pragma unroll
        for (int r=0;r<4;r++)
            #pragma unroll
            for (int c=0;c<4;c++) acc5[r][c] += a[r]*bv[c];
    }
    #pragma unroll
    for (int r=0;r<4;r++){
        ushort4 o;
        o.x=f2bf(-acc5[r][0]); o.y=f2bf(-acc5[r][1]);
        o.z=f2bf(-acc5[r][2]); o.w=f2bf(-acc5[r][3]);
        *(ushort4*)&g1[gbase + (ty*4+r)*DD + tx*4] = o;
    }
}

// ---------------------------------------------------------------------------
// K5: two stacked first-order scans over n=128, in place on bf16 g1/g2.
// ---------------------------------------------------------------------------
__global__ __launch_bounds__(256) void k_scan(
    uint16_t* __restrict__ g1, uint16_t* __restrict__ g2,
    const float* __restrict__ mom, const float* __restrict__ dec)
{
    int blk = blockIdx.x;            // [0,512)
    int arr = blk>>8; int rem = blk&255;
    int bh = rem>>3; int eg = rem&7;
    int e2 = eg*512 + threadIdx.x*2;
    uint16_t* gp = arr ? g2 : g1;
    __shared__ float smg[NN], sdc[NN];
    if (threadIdx.x < NN){
        smg[threadIdx.x] = mom[bh*NN+threadIdx.x];
        sdc[threadIdx.x] = 1.f - dec[bh*NN+threadIdx.x];
    }
    __syncthreads();
    size_t base = (size_t)bh*NN*4096 + e2;
    float ma=0.f, mb=0.f, ua=0.f, ub=0.f;
    for (int t=0;t<NN;t++){
        uint32_t w = *(const uint32_t*)&gp[base + (size_t)t*4096];
        float f0 = bf2f(w&0xffffu), f1 = bf2f(w>>16);
        float mg = smg[t], dc = sdc[t];
        ma = fmaf(mg,ma,f0); ua = fmaf(dc,ua,ma);
        mb = fmaf(mg,mb,f1); ub = fmaf(dc,ub,mb);
        *(uint32_t*)&gp[base + (size_t)t*4096] =
            (uint32_t)f2bf(ua) | ((uint32_t)f2bf(ub)<<16);
    }
}

// ---------------------------------------------------------------------------
// K6: retrieve. x=silu(qc@(w1+u1))@(w2+u2); rmsnorm(d=64)*(1+gamma)*gate -> y
// gate_t layout [b][j][h]. One block per (bh,n). y bf16 merged [b][j][h*64+dk].
// ---------------------------------------------------------------------------
__global__ __launch_bounds__(256) void k_retrieve(
    const uint16_t* __restrict__ qbuf, const uint16_t* __restrict__ u1,
    const uint16_t* __restrict__ u2, const float* __restrict__ w1,
    const float* __restrict__ w2, const float* __restrict__ gamma,
    const float* __restrict__ gate_t, uint16_t* __restrict__ y)
{
    __shared__ float qc[64][64];
    __shared__ float w1p[64][64];
    __shared__ float w2p[64][64];
    __shared__ float hsil[64][64];
    int bhn = blockIdx.x;
    int bh = bhn>>7, n = bhn&127;
    int b = bh>>3, h = bh&7;
    int tid = threadIdx.x, tx = tid&15, ty = tid>>4;
    size_t cbase = ((size_t)bh*TT + n*CC)*DD;
    size_t ub = (size_t)bhn*4096;

    #pragma unroll
    for (int r=0;r<4;r++){
        int row = ty*4+r;
        ushort4 q4 = *(const ushort4*)&qbuf[cbase + row*DD + tx*4];
        qc[row][tx*4+0]=bf2f(q4.x); qc[row][tx*4+1]=bf2f(q4.y);
        qc[row][tx*4+2]=bf2f(q4.z); qc[row][tx*4+3]=bf2f(q4.w);
        float4 wv1 = *(const float4*)&w1[row*DD+tx*4];
        ushort4 u14 = *(const ushort4*)&u1[ub + row*DD + tx*4];
        w1p[row][tx*4+0]=wv1.x+bf2f(u14.x); w1p[row][tx*4+1]=wv1.y+bf2f(u14.y);
        w1p[row][tx*4+2]=wv1.z+bf2f(u14.z); w1p[row][tx*4+3]=wv1.w+bf2f(u14.w);
        float4 wv2 = *(const float4*)&w2[row*DD+tx*4];
        ushort4 u24 = *(const ushort4*)&u2[ub + row*DD + tx*4];
        w2p[row][tx*4+0]=wv2.x+bf2f(u24.x); w2p[row][tx*4+1]=wv2.y+bf2f(u24.y);
        w2p[row][tx*4+2]=wv2.z+bf2f(u24.z); w2p[row][tx*4+3]=wv2.w+bf2f(u24.w);
    }
    __syncthreads();

    float accA[4][4] = {};
    for (int k=0;k<64;k++){
        float a[4], bv[4];
        #pragma unroll
        for (int r=0;r<4;r++) a[r]=qc[ty*4+r][k];
        *(float4*)bv = *(const float4*)&w1p[k][tx*4];
        #pragma unroll
        for (int r=0;r<4;r++)
            #pragma unroll
            for (int c=0;c<4;c++) accA[r][c] += a[r]*bv[c];
    }
    #pragma unroll
    for (int r=0;r<4;r++)
        #pragma unroll
        for (int c=0;c<4;c++){
            float x = accA[r][c];
            hsil[ty*4+r][tx*4+c] = x*sigmoidf_(x);
        }
    __syncthreads();

    float accB[4][4] = {};
    for (int k=0;k<64;k++){
        float a[4], bv[4];
        #pragma unroll
        for (int r=0;r<4;r++) a[r]=hsil[ty*4+r][k];
        *(float4*)bv = *(const float4*)&w2p[k][tx*4];
        #pragma unroll
        for (int r=0;r<4;r++)
            #pragma unroll
            for (int c=0;c<4;c++) accB[r][c] += a[r]*bv[c];
    }
    // row sums of squares: partials into w1p[row][tx] (w1p no longer needed)
    #pragma unroll
    for (int r=0;r<4;r++){
        float p = accB[r][0]*accB[r][0]+accB[r][1]*accB[r][1]
                + accB[r][2]*accB[r][2]+accB[r][3]*accB[r][3];
        w1p[ty*4+r][tx] = p;
    }
    __syncthreads();
    #pragma unroll
    for (int r=0;r<4;r++){
        int row = ty*4+r;
        float rs=0.f;
        #pragma unroll
        for (int i=0;i<16;i++) rs += w1p[row][i];
        float sclv = rsqrtf(rs*(1.0f/DD)+EPS);
        float gt = gate_t[((size_t)b*TT + n*CC + row)*HH + h];
        float4 gm = *(const float4*)&gamma[h*DD + tx*4];
        ushort4 o;
        o.x = f2bf(accB[r][0]*sclv*(1.f+gm.x)*gt);
        o.y = f2bf(accB[r][1]*sclv*(1.f+gm.y)*gt);
        o.z = f2bf(accB[r][2]*sclv*(1.f+gm.z)*gt);
        o.w = f2bf(accB[r][3]*sclv*(1.f+gm.w)*gt);
        *(ushort4*)&y[((size_t)b*TT + n*CC + row)*DIMM + h*DD + tx*4] = o;
    }
}

// ---------------------------------------------------------------------------
// K7: zero pads — q rows j in [8129,8191] (bf16), out rows [0,62] (f32),
//     gate_t rows j in [8129,8191] (f32, read by k_retrieve at n=127)
// ---------------------------------------------------------------------------
__global__ __launch_bounds__(256) void k_zero(
    uint16_t* __restrict__ qbuf, float* __restrict__ out, float* __restrict__ gate_t)
{
    int g = blockIdx.x*256 + threadIdx.x;
    const int QN = BHH*63*DD;          // 129024
    const int ON = BB*63*DIMM;         // 129024
    const int GN = BB*63*HH;           // 2016
    if (g < QN){
        int bh = g/4032; int r = g - bh*4032;
        int j = 8129 + (r>>6); int dk = r&63;
        qbuf[((size_t)bh*TT + j)*DD + dk] = 0;
    } else if (g < QN+ON){
        int g2i = g - QN;
        int b = g2i/(63*512); int r = g2i - b*63*512;
        int t = r>>9; int e = r&511;
        out[((size_t)b*TT + t)*DIMM + e] = 0.f;
    } else if (g < QN+ON+GN){
        int g3 = g - QN - ON;
        int b = g3/(63*HH); int r = g3 - b*63*HH;
        int j = 8129 + (r>>3); int hh = r&7;
        gate_t[((size_t)b*TT + j)*HH + hh] = 0.f;
    }
}

// ---------------------------------------------------------------------------
extern "C" void kernel_launch(void* const* d_in, const int* in_sizes, int n_in,
                              void* d_out, int out_size, void* d_ws, size_t ws_size,
                              hipStream_t stream)
{
    (void)in_sizes; (void)n_in; (void)out_size; (void)ws_size;
    const float* seq    = (const float*)d_in[0];
    const float* w1     = (const float*)d_in[1];
    const float* w2     = (const float*)d_in[2];
    const float* Wq     = (const float*)d_in[3];
    const float* Wkv    = (const float*)d_in[4];
    const float* Wstep  = (const float*)d_in[5];
    const float* Wmom   = (const float*)d_in[6];
    const float* Wdecay = (const float*)d_in[7];
    const float* Wgate  = (const float*)d_in[8];
    const float* Wcomb  = (const float*)d_in[9];
    const float* gamma  = (const float*)d_in[10];
    float* out = (float*)d_out;

    // workspace layout: ~2.26MB fp32 small + 4 x 32MB bf16 = ~130.5MB
    float* scale = (float*)d_ws;          // 32768
    float* lr_t  = scale + 32768;         // 262144  [b][t][h]
    float* gate_t= lr_t + 262144;         // 262144  [b][j][h]
    float* mom   = gate_t + 262144;       // 4096
    float* dec   = mom + 4096;            // 4096
    uint16_t* kb = (uint16_t*)(dec + 4096);  // 16777216 bf16 (q reuses after k_grad)
    uint16_t* vb = kb + 16777216;            // 16777216 bf16 (y reuses after k_retrieve)
    uint16_t* g1 = vb + 16777216;            // 16777216 bf16 (in-place scan -> upd1)
    uint16_t* g2 = g1 + 16777216;            // 16777216 bf16 (in-place scan -> upd2)

    k_norm_scale <<<8192, 256, 0, stream>>>(seq, Wstep, Wgate, scale, lr_t, gate_t);
    k_chunk_gates<<<BB*NN, 512, 0, stream>>>(seq, scale, Wmom, Wdecay, mom, dec);
    k_gemm<0><<<dim3(8, 256), 256, 0, stream>>>(seq, Wkv, scale, kb, vb, 1024);
    k_grad   <<<BHH*NN, 256, 0, stream>>>(kb, vb, lr_t, w1, w2, g1, g2);
    k_scan   <<<512, 256, 0, stream>>>(g1, g2, mom, dec);
    k_gemm<1><<<dim3(4, 256), 256, 0, stream>>>(seq, Wq, scale, kb /*q*/, nullptr, 512);
    k_zero   <<<1017, 256, 0, stream>>>(kb /*q*/, out, gate_t);
    k_retrieve<<<BHH*NN, 256, 0, stream>>>(kb /*q*/, g1, g2, w1, w2, gamma, gate_t, vb /*y*/);
    k_gemm<2><<<dim3(4, 256), 256, 0, stream>>>(vb /*y*/, Wcomb, scale, out, nullptr, 512);
}

// Round 4
// 748.278 us; speedup vs baseline: 2.3429x; 1.8097x over previous
//
#include <hip/hip_runtime.h>
#include <cstdint>

// NeuralMemory forward. MFMA bf16 for big GEMMs; fp32 elsewhere; bf16 storage.
// Shapes (fixed): B=4 T=8192 DIM=512 H=8 D=64 C=64 N=128 BH=32
#define EPS     1.1920929e-07f
#define MAX_LR  0.01f
#define BB      4
#define TT      8192
#define DIMM    512
#define HH      8
#define DD      64
#define CC      64
#define NN      128
#define BHH     32

typedef __attribute__((ext_vector_type(8))) short short8;
typedef __attribute__((ext_vector_type(4))) float f32x4;

__device__ __forceinline__ float sigmoidf_(float x){ return 1.0f/(1.0f+__expf(-x)); }
__device__ __forceinline__ float bf2f(uint32_t lo16){ return __uint_as_float(lo16<<16); }
__device__ __forceinline__ uint16_t f2bf(float f){
    uint32_t x = __float_as_uint(f);
    return (uint16_t)((x + 0x7fffu + ((x>>16)&1u)) >> 16);   // RNE
}
__device__ __forceinline__ uint32_t pk2(float a, float b){
    return (uint32_t)f2bf(a) | ((uint32_t)f2bf(b)<<16);
}

// ---------------------------------------------------------------------------
// K1: wave-per-row rmsnorm scale + lr/gate head-dots. (unchanged from R3)
// ---------------------------------------------------------------------------
__global__ __launch_bounds__(256) void k_norm_scale(
    const float* __restrict__ seq, const float* __restrict__ Wstep,
    const float* __restrict__ Wgate, float* __restrict__ scale,
    float* __restrict__ lr_t, float* __restrict__ gate_t)
{
    int wave = threadIdx.x >> 6, lane = threadIdx.x & 63;
    int row = blockIdx.x*4 + wave;          // b*T + t
    const float4* sp = (const float4*)&seq[(size_t)row*DIMM + lane*8];
    float4 x0 = sp[0], x1 = sp[1];
    float xs[8] = {x0.x,x0.y,x0.z,x0.w,x1.x,x1.y,x1.z,x1.w};
    float ss = 0.f;
    #pragma unroll
    for (int i=0;i<8;i++) ss += xs[i]*xs[i];
    #pragma unroll
    for (int o=32;o;o>>=1) ss += __shfl_xor(ss,o,64);
    float sc = rsqrtf(ss*(1.0f/DIMM)+EPS);
    if (lane==0) scale[row]=sc;

    float d1[8]={0,0,0,0,0,0,0,0}, d2[8]={0,0,0,0,0,0,0,0};
    int idx0 = lane*8;
    #pragma unroll
    for (int i=0;i<8;i++){
        float sv = xs[i]*sc;
        float4 wa = *(const float4*)&Wstep[(idx0+i)*HH];
        float4 wb4= *(const float4*)&Wstep[(idx0+i)*HH+4];
        d1[0]+=sv*wa.x;  d1[1]+=sv*wa.y;  d1[2]+=sv*wa.z;  d1[3]+=sv*wa.w;
        d1[4]+=sv*wb4.x; d1[5]+=sv*wb4.y; d1[6]+=sv*wb4.z; d1[7]+=sv*wb4.w;
        float4 ga = *(const float4*)&Wgate[(idx0+i)*HH];
        float4 gb = *(const float4*)&Wgate[(idx0+i)*HH+4];
        d2[0]+=sv*ga.x; d2[1]+=sv*ga.y; d2[2]+=sv*ga.z; d2[3]+=sv*ga.w;
        d2[4]+=sv*gb.x; d2[5]+=sv*gb.y; d2[6]+=sv*gb.z; d2[7]+=sv*gb.w;
    }
    #pragma unroll
    for (int o=32;o;o>>=1){
        #pragma unroll
        for (int h=0;h<8;h++){
            d1[h]+=__shfl_down(d1[h],o,64);
            d2[h]+=__shfl_down(d2[h],o,64);
        }
    }
    if (lane==0){
        int b = row>>13, t = row&8191;
        float4 l0 = make_float4(sigmoidf_(d1[0])*MAX_LR, sigmoidf_(d1[1])*MAX_LR,
                                sigmoidf_(d1[2])*MAX_LR, sigmoidf_(d1[3])*MAX_LR);
        float4 l1 = make_float4(sigmoidf_(d1[4])*MAX_LR, sigmoidf_(d1[5])*MAX_LR,
                                sigmoidf_(d1[6])*MAX_LR, sigmoidf_(d1[7])*MAX_LR);
        *(float4*)&lr_t[(size_t)row*HH]   = l0;
        *(float4*)&lr_t[(size_t)row*HH+4] = l1;
        int j = t-63;
        if (j>=0){
            size_t go = ((size_t)b*TT + j)*HH;
            float4 g0 = make_float4(sigmoidf_(d2[0]), sigmoidf_(d2[1]),
                                    sigmoidf_(d2[2]), sigmoidf_(d2[3]));
            float4 g1v= make_float4(sigmoidf_(d2[4]), sigmoidf_(d2[5]),
                                    sigmoidf_(d2[6]), sigmoidf_(d2[7]));
            *(float4*)&gate_t[go]   = g0;
            *(float4*)&gate_t[go+4] = g1v;
        }
    }
}

// ---------------------------------------------------------------------------
// K2: chunk means (unchanged)
// ---------------------------------------------------------------------------
__global__ __launch_bounds__(512) void k_chunk_gates(
    const float* __restrict__ seq, const float* __restrict__ scale,
    const float* __restrict__ Wmom, const float* __restrict__ Wdecay,
    float* __restrict__ mom, float* __restrict__ dec)
{
    int blk = blockIdx.x;              // b*N + n
    int b = blk>>7, n = blk&127;
    int tid = threadIdx.x;
    __shared__ float scl[CC];
    if (tid < CC) scl[tid] = scale[b*TT + n*CC + tid];
    __syncthreads();
    size_t base = ((size_t)b*TT + n*CC)*DIMM + tid;
    float acc=0.f;
    #pragma unroll 8
    for (int j=0;j<CC;j++) acc += seq[base + (size_t)j*DIMM]*scl[j];
    __shared__ float sm[DIMM];
    sm[tid] = acc*(1.0f/CC);
    __syncthreads();
    int wid = tid>>6, lane = tid&63;
    float d1=0.f, d2=0.f;
    #pragma unroll
    for (int i=0;i<8;i++){
        int idx=i*64+lane; float sv=sm[idx];
        d1 += sv*Wmom[idx*HH+wid];
        d2 += sv*Wdecay[idx*HH+wid];
    }
    #pragma unroll
    for (int o=32;o;o>>=1){ d1+=__shfl_down(d1,o,64); d2+=__shfl_down(d2,o,64); }
    if (lane==0){
        mom[(b*HH+wid)*NN + n] = sigmoidf_(d1);
        dec[(b*HH+wid)*NN + n] = sigmoidf_(d2);
    }
}

// ---------------------------------------------------------------------------
// K3a: transpose+convert B matrix: in fp32 [512][Ncols] -> out bf16 [Ncols][512]
// ---------------------------------------------------------------------------
__global__ __launch_bounds__(256) void k_transpose(
    const float* __restrict__ in, uint16_t* __restrict__ out, int Ncols)
{
    __shared__ float tile[32][33];
    int bx = blockIdx.x*32;   // n
    int by = blockIdx.y*32;   // k
    int lx = threadIdx.x&31, ly = threadIdx.x>>5;   // 32 x 8
    #pragma unroll
    for (int r=0;r<4;r++)
        tile[ly+8*r][lx] = in[(size_t)(by+ly+8*r)*Ncols + bx+lx];
    __syncthreads();
    #pragma unroll
    for (int r=0;r<4;r++)
        out[(size_t)(bx+ly+8*r)*DIMM + by+lx] = f2bf(tile[lx][ly+8*r]);
}

// ---------------------------------------------------------------------------
// K3: MFMA GEMM  C(M x Ncols) = A(M x 512) @ B(512 x Ncols), B given as
// Bt bf16 [Ncols][512]. 128x128 block tile, 4 waves x (64x64: 4x4 of 16x16),
// BK=64. LDS rows padded to 72 bf16 (144B: 2-way bank aliasing only).
// MODE 0: A=seq*scale fp32 -> bf16; scatter bf16 k (e<512) / v (e>=512)
// MODE 1: same A; row shift j=t-63, bf16 q head-split (skip j<0)
// MODE 2: A=y bf16; row shift t'=j+63, fp32 d_out (skip t'>=8192)
// ---------------------------------------------------------------------------
template<int MODE>
__global__ __launch_bounds__(256) void k_gemm_mfma(
    const void* __restrict__ Av, const uint16_t* __restrict__ Bt,
    const float* __restrict__ scale, void* __restrict__ out0,
    void* __restrict__ out1)
{
    __shared__ uint16_t Asl[128][72];
    __shared__ uint16_t Bsl[128][72];
    __shared__ float sscale[128];
    int tid = threadIdx.x;
    int wave = tid>>6, lane = tid&63;
    int q = lane>>4, col = lane&15;
    int m0 = blockIdx.y*128, n0 = blockIdx.x*128;
    int m_off = (wave&1)*64, n_off = (wave>>1)*64;

    if (MODE!=2){
        if (tid<128) sscale[tid] = scale[m0+tid];
        __syncthreads();
    }

    f32x4 acc[4][4];
    #pragma unroll
    for (int i=0;i<4;i++)
        #pragma unroll
        for (int j=0;j<4;j++) acc[i][j] = (f32x4){0.f,0.f,0.f,0.f};

    for (int k0=0;k0<DIMM;k0+=64){
        // stage A tile (128 rows x 64 k) as bf16
        #pragma unroll
        for (int s=0;s<4;s++){
            int seg = s*256 + tid;           // 1024 segs: row=seg>>3, kk=seg&7
            int row = seg>>3, kk = seg&7;
            if (MODE==2){
                const uint16_t* A = (const uint16_t*)Av;
                uint4 v = *(const uint4*)&A[(size_t)(m0+row)*DIMM + k0 + kk*8];
                *(uint4*)&Asl[row][kk*8] = v;
            } else {
                const float* A = (const float*)Av;
                float sc = sscale[row];
                const float4* ap = (const float4*)&A[(size_t)(m0+row)*DIMM + k0 + kk*8];
                float4 a0 = ap[0], a1 = ap[1];
                uint4 v;
                v.x = pk2(a0.x*sc, a0.y*sc);
                v.y = pk2(a0.z*sc, a0.w*sc);
                v.z = pk2(a1.x*sc, a1.y*sc);
                v.w = pk2(a1.z*sc, a1.w*sc);
                *(uint4*)&Asl[row][kk*8] = v;
            }
        }
        // stage B tile (128 n-rows x 64 k) from Bt
        #pragma unroll
        for (int s=0;s<4;s++){
            int seg = s*256 + tid;
            int row = seg>>3, kk = seg&7;
            uint4 v = *(const uint4*)&Bt[(size_t)(n0+row)*DIMM + k0 + kk*8];
            *(uint4*)&Bsl[row][kk*8] = v;
        }
        __syncthreads();
        #pragma unroll
        for (int ks=0;ks<64;ks+=32){
            short8 af[4], bf[4];
            #pragma unroll
            for (int mt=0;mt<4;mt++)
                af[mt] = *(const short8*)&Asl[m_off + mt*16 + col][ks + q*8];
            #pragma unroll
            for (int nt=0;nt<4;nt++)
                bf[nt] = *(const short8*)&Bsl[n_off + nt*16 + col][ks + q*8];
            #pragma unroll
            for (int mt=0;mt<4;mt++)
                #pragma unroll
                for (int nt=0;nt<4;nt++)
                    acc[mt][nt] = __builtin_amdgcn_mfma_f32_16x16x32_bf16(
                        af[mt], bf[nt], acc[mt][nt], 0, 0, 0);
        }
        __syncthreads();
    }

    // epilogue: C/D layout col=lane&15, row=q*4+reg
    #pragma unroll
    for (int mt=0;mt<4;mt++){
        #pragma unroll
        for (int reg=0;reg<4;reg++){
            int m = m0 + m_off + mt*16 + q*4 + reg;
            int b = m>>13, t = m&8191;
            if (MODE==0){
                #pragma unroll
                for (int nt=0;nt<4;nt++){
                    int e = n0 + n_off + nt*16 + col;
                    uint16_t* basep = (uint16_t*)((e<512) ? out0 : out1);
                    int ee = e & 511;
                    int h = ee>>6, dk = ee&63;
                    basep[((size_t)(b*HH+h)*TT + t)*DD + dk] = f2bf(acc[mt][nt][reg]);
                }
            } else if (MODE==1){
                int j = t-63;
                if (j>=0){
                    #pragma unroll
                    for (int nt=0;nt<4;nt++){
                        int e = n0 + n_off + nt*16 + col;
                        int h = e>>6, dk = e&63;
                        ((uint16_t*)out0)[((size_t)(b*HH+h)*TT + j)*DD + dk] = f2bf(acc[mt][nt][reg]);
                    }
                }
            } else {
                int tp = t + 63;
                if (tp < TT){
                    #pragma unroll
                    for (int nt=0;nt<4;nt++){
                        int e = n0 + n_off + nt*16 + col;
                        ((float*)out0)[((size_t)b*TT + tp)*DIMM + e] = acc[mt][nt][reg];
                    }
                }
            }
        }
    }
}

// ---------------------------------------------------------------------------
// K4: per-chunk MLP gradient (unchanged from R3)
// ---------------------------------------------------------------------------
__global__ __launch_bounds__(256) void k_grad(
    const uint16_t* __restrict__ kbuf, const uint16_t* __restrict__ vbuf,
    const float* __restrict__ lr_t, const float* __restrict__ w1,
    const float* __restrict__ w2, uint16_t* __restrict__ g1, uint16_t* __restrict__ g2)
{
    __shared__ float kc[64][64];
    __shared__ float hs[64][64];
    __shared__ float dx2s[64][64];
    __shared__ float wb[64][64];
    __shared__ float wbT[64][68];
    int bhn = blockIdx.x;
    int bh = bhn>>7, n = bhn&127;
    int b = bh>>3, h = bh&7;
    int tid = threadIdx.x, tx = tid&15, ty = tid>>4;
    size_t cbase = ((size_t)bh*TT + n*CC)*DD;

    #pragma unroll
    for (int r=0;r<4;r++){
        int row = ty*4+r;
        ushort4 k4 = *(const ushort4*)&kbuf[cbase + row*DD + tx*4];
        kc[row][tx*4+0]=bf2f(k4.x); kc[row][tx*4+1]=bf2f(k4.y);
        kc[row][tx*4+2]=bf2f(k4.z); kc[row][tx*4+3]=bf2f(k4.w);
        *(float4*)&wb[row][tx*4] = *(const float4*)&w1[row*DD + tx*4];
    }
    __syncthreads();

    float accA[4][4] = {};
    for (int k=0;k<64;k++){
        float a[4], bv[4];
        #pragma unroll
        for (int r=0;r<4;r++) a[r]=kc[ty*4+r][k];
        *(float4*)bv = *(const float4*)&wb[k][tx*4];
        #pragma unroll
        for (int r=0;r<4;r++)
            #pragma unroll
            for (int c=0;c<4;c++) accA[r][c] += a[r]*bv[c];
    }
    float sg[4][4], hr[4][4];
    #pragma unroll
    for (int r=0;r<4;r++)
        #pragma unroll
        for (int c=0;c<4;c++){
            float x = accA[r][c];
            float sgm = sigmoidf_(x);
            sg[r][c]=sgm; hr[r][c]=x*sgm;
            hs[ty*4+r][tx*4+c] = x*sgm;
        }
    __syncthreads();
    #pragma unroll
    for (int r=0;r<4;r++){
        int row = ty*4+r;
        float4 wv = *(const float4*)&w2[row*DD + tx*4];
        *(float4*)&wb[row][tx*4] = wv;
        wbT[tx*4+0][row]=wv.x; wbT[tx*4+1][row]=wv.y;
        wbT[tx*4+2][row]=wv.z; wbT[tx*4+3][row]=wv.w;
    }
    __syncthreads();

    float acc2[4][4] = {};
    for (int k=0;k<64;k++){
        float a[4], bv[4];
        #pragma unroll
        for (int r=0;r<4;r++) a[r]=hs[ty*4+r][k];
        *(float4*)bv = *(const float4*)&wb[k][tx*4];
        #pragma unroll
        for (int r=0;r<4;r++)
            #pragma unroll
            for (int c=0;c<4;c++) acc2[r][c] += a[r]*bv[c];
    }
    #pragma unroll
    for (int r=0;r<4;r++){
        int row = ty*4+r;
        float lrv = lr_t[((size_t)b*TT + n*CC + row)*HH + h];
        ushort4 v4 = *(const ushort4*)&vbuf[cbase + row*DD + tx*4];
        float vz[4] = {bf2f(v4.x),bf2f(v4.y),bf2f(v4.z),bf2f(v4.w)};
        #pragma unroll
        for (int c=0;c<4;c++)
            dx2s[row][tx*4+c] = (2.0f/DD)*lrv*(acc2[r][c]-vz[c]);
    }
    __syncthreads();

    float acc3[4][4] = {};
    for (int i=0;i<64;i++){
        float a[4], bv[4];
        #pragma unroll
        for (int r=0;r<4;r++) a[r]=hs[i][ty*4+r];
        *(float4*)bv = *(const float4*)&dx2s[i][tx*4];
        #pragma unroll
        for (int r=0;r<4;r++)
            #pragma unroll
            for (int c=0;c<4;c++) acc3[r][c] += a[r]*bv[c];
    }
    size_t gbase = (size_t)bhn*4096;
    #pragma unroll
    for (int r=0;r<4;r++){
        ushort4 o;
        o.x=f2bf(-acc3[r][0]); o.y=f2bf(-acc3[r][1]);
        o.z=f2bf(-acc3[r][2]); o.w=f2bf(-acc3[r][3]);
        *(ushort4*)&g2[gbase + (ty*4+r)*DD + tx*4] = o;
    }
    __syncthreads();

    float acc4[4][4] = {};
    for (int qq=0;qq<64;qq++){
        float a[4], bv[4];
        #pragma unroll
        for (int r=0;r<4;r++) a[r]=dx2s[ty*4+r][qq];
        *(float4*)bv = *(const float4*)&wbT[qq][tx*4];
        #pragma unroll
        for (int r=0;r<4;r++)
            #pragma unroll
            for (int c=0;c<4;c++) acc4[r][c] += a[r]*bv[c];
    }
    #pragma unroll
    for (int r=0;r<4;r++)
        #pragma unroll
        for (int c=0;c<4;c++){
            float dsilu = sg[r][c] + hr[r][c]*(1.f-sg[r][c]);
            hs[ty*4+r][tx*4+c] = acc4[r][c]*dsilu;
        }
    __syncthreads();

    float acc5[4][4] = {};
    for (int i=0;i<64;i++){
        float a[4], bv[4];
        #pragma unroll
        for (int r=0;r<4;r++) a[r]=kc[i][ty*4+r];
        *(float4*)bv = *(const float4*)&hs[i][tx*4];
        #pragma unroll
        for (int r=0;r<4;r++)
            #pragma unroll
            for (int c=0;c<4;c++) acc5[r][c] += a[r]*bv[c];
    }
    #pragma unroll
    for (int r=0;r<4;r++){
        ushort4 o;
        o.x=f2bf(-acc5[r][0]); o.y=f2bf(-acc5[r][1]);
        o.z=f2bf(-acc5[r][2]); o.w=f2bf(-acc5[r][3]);
        *(ushort4*)&g1[gbase + (ty*4+r)*DD + tx*4] = o;
    }
}

// ---------------------------------------------------------------------------
// K5: scans (unchanged)
// ---------------------------------------------------------------------------
__global__ __launch_bounds__(256) void k_scan(
    uint16_t* __restrict__ g1, uint16_t* __restrict__ g2,
    const float* __restrict__ mom, const float* __restrict__ dec)
{
    int blk = blockIdx.x;            // [0,512)
    int arr = blk>>8; int rem = blk&255;
    int bh = rem>>3; int eg = rem&7;
    int e2 = eg*512 + threadIdx.x*2;
    uint16_t* gp = arr ? g2 : g1;
    __shared__ float smg[NN], sdc[NN];
    if (threadIdx.x < NN){
        smg[threadIdx.x] = mom[bh*NN+threadIdx.x];
        sdc[threadIdx.x] = 1.f - dec[bh*NN+threadIdx.x];
    }
    __syncthreads();
    size_t base = (size_t)bh*NN*4096 + e2;
    float ma=0.f, mb=0.f, ua=0.f, ub=0.f;
    for (int t=0;t<NN;t++){
        uint32_t w = *(const uint32_t*)&gp[base + (size_t)t*4096];
        float f0 = bf2f(w&0xffffu), f1 = bf2f(w>>16);
        float mg = smg[t], dc = sdc[t];
        ma = fmaf(mg,ma,f0); ua = fmaf(dc,ua,ma);
        mb = fmaf(mg,mb,f1); ub = fmaf(dc,ub,mb);
        *(uint32_t*)&gp[base + (size_t)t*4096] =
            (uint32_t)f2bf(ua) | ((uint32_t)f2bf(ub)<<16);
    }
}

// ---------------------------------------------------------------------------
// K6: retrieve (unchanged)
// ---------------------------------------------------------------------------
__global__ __launch_bounds__(256) void k_retrieve(
    const uint16_t* __restrict__ qbuf, const uint16_t* __restrict__ u1,
    const uint16_t* __restrict__ u2, const float* __restrict__ w1,
    const float* __restrict__ w2, const float* __restrict__ gamma,
    const float* __restrict__ gate_t, uint16_t* __restrict__ y)
{
    __shared__ float qc[64][64];
    __shared__ float w1p[64][64];
    __shared__ float w2p[64][64];
    __shared__ float hsil[64][64];
    int bhn = blockIdx.x;
    int bh = bhn>>7, n = bhn&127;
    int b = bh>>3, h = bh&7;
    int tid = threadIdx.x, tx = tid&15, ty = tid>>4;
    size_t cbase = ((size_t)bh*TT + n*CC)*DD;
    size_t ub = (size_t)bhn*4096;

    #pragma unroll
    for (int r=0;r<4;r++){
        int row = ty*4+r;
        ushort4 q4 = *(const ushort4*)&qbuf[cbase + row*DD + tx*4];
        qc[row][tx*4+0]=bf2f(q4.x); qc[row][tx*4+1]=bf2f(q4.y);
        qc[row][tx*4+2]=bf2f(q4.z); qc[row][tx*4+3]=bf2f(q4.w);
        float4 wv1 = *(const float4*)&w1[row*DD+tx*4];
        ushort4 u14 = *(const ushort4*)&u1[ub + row*DD + tx*4];
        w1p[row][tx*4+0]=wv1.x+bf2f(u14.x); w1p[row][tx*4+1]=wv1.y+bf2f(u14.y);
        w1p[row][tx*4+2]=wv1.z+bf2f(u14.z); w1p[row][tx*4+3]=wv1.w+bf2f(u14.w);
        float4 wv2 = *(const float4*)&w2[row*DD+tx*4];
        ushort4 u24 = *(const ushort4*)&u2[ub + row*DD + tx*4];
        w2p[row][tx*4+0]=wv2.x+bf2f(u24.x); w2p[row][tx*4+1]=wv2.y+bf2f(u24.y);
        w2p[row][tx*4+2]=wv2.z+bf2f(u24.z); w2p[row][tx*4+3]=wv2.w+bf2f(u24.w);
    }
    __syncthreads();

    float accA[4][4] = {};
    for (int k=0;k<64;k++){
        float a[4], bv[4];
        #pragma unroll
        for (int r=0;r<4;r++) a[r]=qc[ty*4+r][k];
        *(float4*)bv = *(const float4*)&w1p[k][tx*4];
        #pragma unroll
        for (int r=0;r<4;r++)
            #pragma unroll
            for (int c=0;c<4;c++) accA[r][c] += a[r]*bv[c];
    }
    #pragma unroll
    for (int r=0;r<4;r++)
        #pragma unroll
        for (int c=0;c<4;c++){
            float x = accA[r][c];
            hsil[ty*4+r][tx*4+c] = x*sigmoidf_(x);
        }
    __syncthreads();

    float accB[4][4] = {};
    for (int k=0;k<64;k++){
        float a[4], bv[4];
        #pragma unroll
        for (int r=0;r<4;r++) a[r]=hsil[ty*4+r][k];
        *(float4*)bv = *(const float4*)&w2p[k][tx*4];
        #pragma unroll
        for (int r=0;r<4;r++)
            #pragma unroll
            for (int c=0;c<4;c++) accB[r][c] += a[r]*bv[c];
    }
    #pragma unroll
    for (int r=0;r<4;r++){
        float p = accB[r][0]*accB[r][0]+accB[r][1]*accB[r][1]
                + accB[r][2]*accB[r][2]+accB[r][3]*accB[r][3];
        w1p[ty*4+r][tx] = p;
    }
    __syncthreads();
    #pragma unroll
    for (int r=0;r<4;r++){
        int row = ty*4+r;
        float rs=0.f;
        #pragma unroll
        for (int i=0;i<16;i++) rs += w1p[row][i];
        float sclv = rsqrtf(rs*(1.0f/DD)+EPS);
        float gt = gate_t[((size_t)b*TT + n*CC + row)*HH + h];
        float4 gm = *(const float4*)&gamma[h*DD + tx*4];
        ushort4 o;
        o.x = f2bf(accB[r][0]*sclv*(1.f+gm.x)*gt);
        o.y = f2bf(accB[r][1]*sclv*(1.f+gm.y)*gt);
        o.z = f2bf(accB[r][2]*sclv*(1.f+gm.z)*gt);
        o.w = f2bf(accB[r][3]*sclv*(1.f+gm.w)*gt);
        *(ushort4*)&y[((size_t)b*TT + n*CC + row)*DIMM + h*DD + tx*4] = o;
    }
}

// ---------------------------------------------------------------------------
// K7: zero pads (unchanged)
// ---------------------------------------------------------------------------
__global__ __launch_bounds__(256) void k_zero(
    uint16_t* __restrict__ qbuf, float* __restrict__ out, float* __restrict__ gate_t)
{
    int g = blockIdx.x*256 + threadIdx.x;
    const int QN = BHH*63*DD;          // 129024
    const int ON = BB*63*DIMM;         // 129024
    const int GN = BB*63*HH;           // 2016
    if (g < QN){
        int bh = g/4032; int r = g - bh*4032;
        int j = 8129 + (r>>6); int dk = r&63;
        qbuf[((size_t)bh*TT + j)*DD + dk] = 0;
    } else if (g < QN+ON){
        int g2i = g - QN;
        int b = g2i/(63*512); int r = g2i - b*63*512;
        int t = r>>9; int e = r&511;
        out[((size_t)b*TT + t)*DIMM + e] = 0.f;
    } else if (g < QN+ON+GN){
        int g3 = g - QN - ON;
        int b = g3/(63*HH); int r = g3 - b*63*HH;
        int j = 8129 + (r>>3); int hh = r&7;
        gate_t[((size_t)b*TT + j)*HH + hh] = 0.f;
    }
}

// ---------------------------------------------------------------------------
extern "C" void kernel_launch(void* const* d_in, const int* in_sizes, int n_in,
                              void* d_out, int out_size, void* d_ws, size_t ws_size,
                              hipStream_t stream)
{
    (void)in_sizes; (void)n_in; (void)out_size; (void)ws_size;
    const float* seq    = (const float*)d_in[0];
    const float* w1     = (const float*)d_in[1];
    const float* w2     = (const float*)d_in[2];
    const float* Wq     = (const float*)d_in[3];
    const float* Wkv    = (const float*)d_in[4];
    const float* Wstep  = (const float*)d_in[5];
    const float* Wmom   = (const float*)d_in[6];
    const float* Wdecay = (const float*)d_in[7];
    const float* Wgate  = (const float*)d_in[8];
    const float* Wcomb  = (const float*)d_in[9];
    const float* gamma  = (const float*)d_in[10];
    float* out = (float*)d_out;

    // workspace: small fp32 (~2.26MB) + Bt bf16 (2MB) + 4 x 32MB bf16
    float* scale = (float*)d_ws;          // 32768
    float* lr_t  = scale + 32768;         // 262144  [b][t][h]
    float* gate_t= lr_t + 262144;         // 262144  [b][j][h]
    float* mom   = gate_t + 262144;       // 4096
    float* dec   = mom + 4096;            // 4096
    uint16_t* btkv = (uint16_t*)(dec + 4096);  // 1024*512 bf16 [n][k]
    uint16_t* btq  = btkv + 1024*512;          // 512*512
    uint16_t* btc  = btq  + 512*512;           // 512*512
    uint16_t* kb = btc + 512*512;            // 16777216 bf16 (q reuses after k_grad)
    uint16_t* vb = kb + 16777216;            // 16777216 bf16 (y reuses after k_retrieve)
    uint16_t* g1 = vb + 16777216;            // 16777216 bf16 (scan in-place -> upd1)
    uint16_t* g2 = g1 + 16777216;            // 16777216 bf16 (scan in-place -> upd2)

    k_transpose<<<dim3(32,16), 256, 0, stream>>>(Wkv,   btkv, 1024);
    k_transpose<<<dim3(16,16), 256, 0, stream>>>(Wq,    btq,  512);
    k_transpose<<<dim3(16,16), 256, 0, stream>>>(Wcomb, btc,  512);
    k_norm_scale <<<8192, 256, 0, stream>>>(seq, Wstep, Wgate, scale, lr_t, gate_t);
    k_chunk_gates<<<BB*NN, 512, 0, stream>>>(seq, scale, Wmom, Wdecay, mom, dec);
    k_gemm_mfma<0><<<dim3(8, 256), 256, 0, stream>>>(seq, btkv, scale, kb, vb);
    k_grad   <<<BHH*NN, 256, 0, stream>>>(kb, vb, lr_t, w1, w2, g1, g2);
    k_scan   <<<512, 256, 0, stream>>>(g1, g2, mom, dec);
    k_gemm_mfma<1><<<dim3(4, 256), 256, 0, stream>>>(seq, btq, scale, kb /*q*/, nullptr);
    k_zero   <<<1017, 256, 0, stream>>>(kb /*q*/, out, gate_t);
    k_retrieve<<<BHH*NN, 256, 0, stream>>>(kb /*q*/, g1, g2, w1, w2, gamma, gate_t, vb /*y*/);
    k_gemm_mfma<2><<<dim3(4, 256), 256, 0, stream>>>(vb /*y*/, btc, nullptr, out, nullptr);
}

// Round 5
// 557.782 us; speedup vs baseline: 3.1431x; 1.3415x over previous
//
#include <hip/hip_runtime.h>
#include <cstdint>

// NeuralMemory forward. MFMA bf16 for big GEMMs + per-chunk MLP grad/retrieve.
// Shapes (fixed): B=4 T=8192 DIM=512 H=8 D=64 C=64 N=128 BH=32
// g1/g2 (surprises->updates) stored TRANSPOSED [d_out][d_in]; scan is
// layout-agnostic and retrieve's MFMA B-fragments want (w+u)^T rows anyway.
#define EPS     1.1920929e-07f
#define MAX_LR  0.01f
#define BB      4
#define TT      8192
#define DIMM    512
#define HH      8
#define DD      64
#define CC      64
#define NN      128
#define BHH     32
#define LDSP    72      // LDS row stride (bf16): 144B -> 16B aligned, free 2-way alias

typedef __attribute__((ext_vector_type(8))) short short8;
typedef __attribute__((ext_vector_type(4))) float f32x4;

__device__ __forceinline__ float sigmoidf_(float x){ return 1.0f/(1.0f+__expf(-x)); }
__device__ __forceinline__ float bf2f(uint32_t lo16){ return __uint_as_float(lo16<<16); }
__device__ __forceinline__ uint16_t f2bf(float f){
    uint32_t x = __float_as_uint(f);
    return (uint16_t)((x + 0x7fffu + ((x>>16)&1u)) >> 16);   // RNE
}
__device__ __forceinline__ uint32_t pk2(float a, float b){
    return (uint32_t)f2bf(a) | ((uint32_t)f2bf(b)<<16);
}

// 64x64x64 GEMM slice: wave `strip` computes rows [strip*16,strip*16+16) of
// C = A @ B, A staged [m][k] (stride LDSP), B staged as X[n][k] (= B^T rows).
// acc[nt] covers cols nt*16+col. Verified layout (same as k_gemm_mfma R4).
__device__ __forceinline__ void gemm64(const uint16_t* A, const uint16_t* B,
                                       int strip, int q, int col, f32x4* acc)
{
    #pragma unroll
    for (int ks=0; ks<64; ks+=32){
        short8 af = *(const short8*)&A[(strip*16+col)*LDSP + ks + q*8];
        #pragma unroll
        for (int nt=0;nt<4;nt++){
            short8 bf = *(const short8*)&B[(nt*16+col)*LDSP + ks + q*8];
            acc[nt] = __builtin_amdgcn_mfma_f32_16x16x32_bf16(af, bf, acc[nt], 0,0,0);
        }
    }
}

// ---------------------------------------------------------------------------
// K1: wave-per-row rmsnorm scale + lr/gate head-dots. (unchanged)
// ---------------------------------------------------------------------------
__global__ __launch_bounds__(256) void k_norm_scale(
    const float* __restrict__ seq, const float* __restrict__ Wstep,
    const float* __restrict__ Wgate, float* __restrict__ scale,
    float* __restrict__ lr_t, float* __restrict__ gate_t)
{
    int wave = threadIdx.x >> 6, lane = threadIdx.x & 63;
    int row = blockIdx.x*4 + wave;          // b*T + t
    const float4* sp = (const float4*)&seq[(size_t)row*DIMM + lane*8];
    float4 x0 = sp[0], x1 = sp[1];
    float xs[8] = {x0.x,x0.y,x0.z,x0.w,x1.x,x1.y,x1.z,x1.w};
    float ss = 0.f;
    #pragma unroll
    for (int i=0;i<8;i++) ss += xs[i]*xs[i];
    #pragma unroll
    for (int o=32;o;o>>=1) ss += __shfl_xor(ss,o,64);
    float sc = rsqrtf(ss*(1.0f/DIMM)+EPS);
    if (lane==0) scale[row]=sc;

    float d1[8]={0,0,0,0,0,0,0,0}, d2[8]={0,0,0,0,0,0,0,0};
    int idx0 = lane*8;
    #pragma unroll
    for (int i=0;i<8;i++){
        float sv = xs[i]*sc;
        float4 wa = *(const float4*)&Wstep[(idx0+i)*HH];
        float4 wb4= *(const float4*)&Wstep[(idx0+i)*HH+4];
        d1[0]+=sv*wa.x;  d1[1]+=sv*wa.y;  d1[2]+=sv*wa.z;  d1[3]+=sv*wa.w;
        d1[4]+=sv*wb4.x; d1[5]+=sv*wb4.y; d1[6]+=sv*wb4.z; d1[7]+=sv*wb4.w;
        float4 ga = *(const float4*)&Wgate[(idx0+i)*HH];
        float4 gb = *(const float4*)&Wgate[(idx0+i)*HH+4];
        d2[0]+=sv*ga.x; d2[1]+=sv*ga.y; d2[2]+=sv*ga.z; d2[3]+=sv*ga.w;
        d2[4]+=sv*gb.x; d2[5]+=sv*gb.y; d2[6]+=sv*gb.z; d2[7]+=sv*gb.w;
    }
    #pragma unroll
    for (int o=32;o;o>>=1){
        #pragma unroll
        for (int h=0;h<8;h++){
            d1[h]+=__shfl_down(d1[h],o,64);
            d2[h]+=__shfl_down(d2[h],o,64);
        }
    }
    if (lane==0){
        int b = row>>13, t = row&8191;
        float4 l0 = make_float4(sigmoidf_(d1[0])*MAX_LR, sigmoidf_(d1[1])*MAX_LR,
                                sigmoidf_(d1[2])*MAX_LR, sigmoidf_(d1[3])*MAX_LR);
        float4 l1 = make_float4(sigmoidf_(d1[4])*MAX_LR, sigmoidf_(d1[5])*MAX_LR,
                                sigmoidf_(d1[6])*MAX_LR, sigmoidf_(d1[7])*MAX_LR);
        *(float4*)&lr_t[(size_t)row*HH]   = l0;
        *(float4*)&lr_t[(size_t)row*HH+4] = l1;
        int j = t-63;
        if (j>=0){
            size_t go = ((size_t)b*TT + j)*HH;
            float4 g0 = make_float4(sigmoidf_(d2[0]), sigmoidf_(d2[1]),
                                    sigmoidf_(d2[2]), sigmoidf_(d2[3]));
            float4 g1v= make_float4(sigmoidf_(d2[4]), sigmoidf_(d2[5]),
                                    sigmoidf_(d2[6]), sigmoidf_(d2[7]));
            *(float4*)&gate_t[go]   = g0;
            *(float4*)&gate_t[go+4] = g1v;
        }
    }
}

// ---------------------------------------------------------------------------
// K2: chunk means (unchanged)
// ---------------------------------------------------------------------------
__global__ __launch_bounds__(512) void k_chunk_gates(
    const float* __restrict__ seq, const float* __restrict__ scale,
    const float* __restrict__ Wmom, const float* __restrict__ Wdecay,
    float* __restrict__ mom, float* __restrict__ dec)
{
    int blk = blockIdx.x;              // b*N + n
    int b = blk>>7, n = blk&127;
    int tid = threadIdx.x;
    __shared__ float scl[CC];
    if (tid < CC) scl[tid] = scale[b*TT + n*CC + tid];
    __syncthreads();
    size_t base = ((size_t)b*TT + n*CC)*DIMM + tid;
    float acc=0.f;
    #pragma unroll 8
    for (int j=0;j<CC;j++) acc += seq[base + (size_t)j*DIMM]*scl[j];
    __shared__ float sm[DIMM];
    sm[tid] = acc*(1.0f/CC);
    __syncthreads();
    int wid = tid>>6, lane = tid&63;
    float d1=0.f, d2=0.f;
    #pragma unroll
    for (int i=0;i<8;i++){
        int idx=i*64+lane; float sv=sm[idx];
        d1 += sv*Wmom[idx*HH+wid];
        d2 += sv*Wdecay[idx*HH+wid];
    }
    #pragma unroll
    for (int o=32;o;o>>=1){ d1+=__shfl_down(d1,o,64); d2+=__shfl_down(d2,o,64); }
    if (lane==0){
        mom[(b*HH+wid)*NN + n] = sigmoidf_(d1);
        dec[(b*HH+wid)*NN + n] = sigmoidf_(d2);
    }
}

// ---------------------------------------------------------------------------
// K3a: transpose+convert B matrix (unchanged)
// ---------------------------------------------------------------------------
__global__ __launch_bounds__(256) void k_transpose(
    const float* __restrict__ in, uint16_t* __restrict__ out, int Ncols)
{
    __shared__ float tile[32][33];
    int bx = blockIdx.x*32;   // n
    int by = blockIdx.y*32;   // k
    int lx = threadIdx.x&31, ly = threadIdx.x>>5;   // 32 x 8
    #pragma unroll
    for (int r=0;r<4;r++)
        tile[ly+8*r][lx] = in[(size_t)(by+ly+8*r)*Ncols + bx+lx];
    __syncthreads();
    #pragma unroll
    for (int r=0;r<4;r++)
        out[(size_t)(bx+ly+8*r)*DIMM + by+lx] = f2bf(tile[lx][ly+8*r]);
}

// ---------------------------------------------------------------------------
// K3: MFMA GEMM (unchanged from R4)
// ---------------------------------------------------------------------------
template<int MODE>
__global__ __launch_bounds__(256) void k_gemm_mfma(
    const void* __restrict__ Av, const uint16_t* __restrict__ Bt,
    const float* __restrict__ scale, void* __restrict__ out0,
    void* __restrict__ out1)
{
    __shared__ uint16_t Asl[128][72];
    __shared__ uint16_t Bsl[128][72];
    __shared__ float sscale[128];
    int tid = threadIdx.x;
    int wave = tid>>6, lane = tid&63;
    int q = lane>>4, col = lane&15;
    int m0 = blockIdx.y*128, n0 = blockIdx.x*128;
    int m_off = (wave&1)*64, n_off = (wave>>1)*64;

    if (MODE!=2){
        if (tid<128) sscale[tid] = scale[m0+tid];
        __syncthreads();
    }

    f32x4 acc[4][4];
    #pragma unroll
    for (int i=0;i<4;i++)
        #pragma unroll
        for (int j=0;j<4;j++) acc[i][j] = (f32x4){0.f,0.f,0.f,0.f};

    for (int k0=0;k0<DIMM;k0+=64){
        #pragma unroll
        for (int s=0;s<4;s++){
            int seg = s*256 + tid;
            int row = seg>>3, kk = seg&7;
            if (MODE==2){
                const uint16_t* A = (const uint16_t*)Av;
                uint4 v = *(const uint4*)&A[(size_t)(m0+row)*DIMM + k0 + kk*8];
                *(uint4*)&Asl[row][kk*8] = v;
            } else {
                const float* A = (const float*)Av;
                float sc = sscale[row];
                const float4* ap = (const float4*)&A[(size_t)(m0+row)*DIMM + k0 + kk*8];
                float4 a0 = ap[0], a1 = ap[1];
                uint4 v;
                v.x = pk2(a0.x*sc, a0.y*sc);
                v.y = pk2(a0.z*sc, a0.w*sc);
                v.z = pk2(a1.x*sc, a1.y*sc);
                v.w = pk2(a1.z*sc, a1.w*sc);
                *(uint4*)&Asl[row][kk*8] = v;
            }
        }
        #pragma unroll
        for (int s=0;s<4;s++){
            int seg = s*256 + tid;
            int row = seg>>3, kk = seg&7;
            uint4 v = *(const uint4*)&Bt[(size_t)(n0+row)*DIMM + k0 + kk*8];
            *(uint4*)&Bsl[row][kk*8] = v;
        }
        __syncthreads();
        #pragma unroll
        for (int ks=0;ks<64;ks+=32){
            short8 af[4], bf[4];
            #pragma unroll
            for (int mt=0;mt<4;mt++)
                af[mt] = *(const short8*)&Asl[m_off + mt*16 + col][ks + q*8];
            #pragma unroll
            for (int nt=0;nt<4;nt++)
                bf[nt] = *(const short8*)&Bsl[n_off + nt*16 + col][ks + q*8];
            #pragma unroll
            for (int mt=0;mt<4;mt++)
                #pragma unroll
                for (int nt=0;nt<4;nt++)
                    acc[mt][nt] = __builtin_amdgcn_mfma_f32_16x16x32_bf16(
                        af[mt], bf[nt], acc[mt][nt], 0, 0, 0);
        }
        __syncthreads();
    }

    #pragma unroll
    for (int mt=0;mt<4;mt++){
        #pragma unroll
        for (int reg=0;reg<4;reg++){
            int m = m0 + m_off + mt*16 + q*4 + reg;
            int b = m>>13, t = m&8191;
            if (MODE==0){
                #pragma unroll
                for (int nt=0;nt<4;nt++){
                    int e = n0 + n_off + nt*16 + col;
                    uint16_t* basep = (uint16_t*)((e<512) ? out0 : out1);
                    int ee = e & 511;
                    int h = ee>>6, dk = ee&63;
                    basep[((size_t)(b*HH+h)*TT + t)*DD + dk] = f2bf(acc[mt][nt][reg]);
                }
            } else if (MODE==1){
                int j = t-63;
                if (j>=0){
                    #pragma unroll
                    for (int nt=0;nt<4;nt++){
                        int e = n0 + n_off + nt*16 + col;
                        int h = e>>6, dk = e&63;
                        ((uint16_t*)out0)[((size_t)(b*HH+h)*TT + j)*DD + dk] = f2bf(acc[mt][nt][reg]);
                    }
                }
            } else {
                int tp = t + 63;
                if (tp < TT){
                    #pragma unroll
                    for (int nt=0;nt<4;nt++){
                        int e = n0 + n_off + nt*16 + col;
                        ((float*)out0)[((size_t)b*TT + tp)*DIMM + e] = acc[mt][nt][reg];
                    }
                }
            }
        }
    }
}

// ---------------------------------------------------------------------------
// K4: per-chunk MLP gradient via MFMA. One block per (bh,n), 4 waves.
// Outputs -g1^T, -g2^T bf16 at [(bh*N+n)*4096 + dout*64 + din].
// LDS slots (bf16 64xLDSP): s0 kcB[tok][p], s1 kcT[p][tok], s2 w1T[d1][p]->dxB[tok][d2],
// s3 w2T[d2][d1]->dx1T[d1][tok], s4 w2b[d1][d2], s5 hA[d1][tok], s6 hB[tok][d1]->dxA[d2][tok],
// s7 vB[tok][d2].
// ---------------------------------------------------------------------------
__global__ __launch_bounds__(256) void k_grad(
    const uint16_t* __restrict__ kbuf, const uint16_t* __restrict__ vbuf,
    const float* __restrict__ lr_t, const float* __restrict__ w1,
    const float* __restrict__ w2, uint16_t* __restrict__ g1T, uint16_t* __restrict__ g2T)
{
    __shared__ uint16_t lds[8*64*LDSP];
    __shared__ float lr_sh[64];
    uint16_t* kcB  = lds + 0*64*LDSP;
    uint16_t* kcT  = lds + 1*64*LDSP;
    uint16_t* w1T  = lds + 2*64*LDSP;   // -> dxB
    uint16_t* w2T  = lds + 3*64*LDSP;   // -> dx1T
    uint16_t* w2b  = lds + 4*64*LDSP;
    uint16_t* hA   = lds + 5*64*LDSP;
    uint16_t* hB   = lds + 6*64*LDSP;   // -> dxA
    uint16_t* vB   = lds + 7*64*LDSP;
    uint16_t* dxB  = w1T;
    uint16_t* dx1T = w2T;
    uint16_t* dxA  = hB;

    int bhn = blockIdx.x;
    int bh = bhn>>7, n = bhn&127;
    int b = bh>>3, h = bh&7;
    int tid = threadIdx.x, tx = tid&15, ty = tid>>4;
    int w = tid>>6, lane = tid&63, q = lane>>4, col = lane&15;
    size_t cbase = ((size_t)bh*TT + n*CC)*DD;

    // ---- stage ----
    #pragma unroll
    for (int r=0;r<4;r++){
        int row = ty*4+r;
        ushort4 k4 = *(const ushort4*)&kbuf[cbase + row*DD + tx*4];
        *(ushort4*)&kcB[row*LDSP + tx*4] = k4;
        kcT[(tx*4+0)*LDSP + row] = k4.x;
        kcT[(tx*4+1)*LDSP + row] = k4.y;
        kcT[(tx*4+2)*LDSP + row] = k4.z;
        kcT[(tx*4+3)*LDSP + row] = k4.w;
        ushort4 v4 = *(const ushort4*)&vbuf[cbase + row*DD + tx*4];
        *(ushort4*)&vB[row*LDSP + tx*4] = v4;
        float4 w1v = *(const float4*)&w1[row*DD + tx*4];
        w1T[(tx*4+0)*LDSP + row] = f2bf(w1v.x);
        w1T[(tx*4+1)*LDSP + row] = f2bf(w1v.y);
        w1T[(tx*4+2)*LDSP + row] = f2bf(w1v.z);
        w1T[(tx*4+3)*LDSP + row] = f2bf(w1v.w);
        float4 w2v = *(const float4*)&w2[row*DD + tx*4];
        w2T[(tx*4+0)*LDSP + row] = f2bf(w2v.x);
        w2T[(tx*4+1)*LDSP + row] = f2bf(w2v.y);
        w2T[(tx*4+2)*LDSP + row] = f2bf(w2v.z);
        w2T[(tx*4+3)*LDSP + row] = f2bf(w2v.w);
        ushort4 wb4;
        wb4.x=f2bf(w2v.x); wb4.y=f2bf(w2v.y); wb4.z=f2bf(w2v.z); wb4.w=f2bf(w2v.w);
        *(ushort4*)&w2b[row*LDSP + tx*4] = wb4;
    }
    if (tid < 64) lr_sh[tid] = lr_t[((size_t)b*TT + n*CC + tid)*HH + h];
    __syncthreads();

    // ---- G1: x1 = kc @ w1 ; h = silu(x1). C/D rows=token(strip), cols=d1 ----
    f32x4 a1[4];
    #pragma unroll
    for (int i=0;i<4;i++) a1[i]=(f32x4){0.f,0.f,0.f,0.f};
    gemm64(kcB, w1T, w, q, col, a1);
    float sg[16], hr[16];
    #pragma unroll
    for (int nt=0;nt<4;nt++)
        #pragma unroll
        for (int reg=0;reg<4;reg++){
            int idx = nt*4+reg;
            float x = a1[nt][reg];
            float sgm = sigmoidf_(x);
            sg[idx]=sgm; hr[idx]=x*sgm;
            int token = w*16 + q*4 + reg;
            int d1 = nt*16 + col;
            uint16_t hv = f2bf(x*sgm);
            hB[token*LDSP + d1] = hv;
            hA[d1*LDSP + token] = hv;
        }
    __syncthreads();

    // ---- G2: x2 = h @ w2 ; dx2 = (2/D)*lr*(x2 - v) ----
    f32x4 a2[4];
    #pragma unroll
    for (int i=0;i<4;i++) a2[i]=(f32x4){0.f,0.f,0.f,0.f};
    gemm64(hB, w2T, w, q, col, a2);
    __syncthreads();   // hB/w1T reads done before overwrite with dxA/dxB
    #pragma unroll
    for (int nt=0;nt<4;nt++)
        #pragma unroll
        for (int reg=0;reg<4;reg++){
            int token = w*16 + q*4 + reg;
            int d2 = nt*16 + col;
            float vv = bf2f(vB[token*LDSP + d2]);
            float dx = (2.0f/DD)*lr_sh[token]*(a2[nt][reg]-vv);
            uint16_t dv = f2bf(dx);
            dxA[d2*LDSP + token] = dv;
            dxB[token*LDSP + d2] = dv;
        }
    __syncthreads();

    // ---- G3: g2^T = dx2^T @ h  (rows=d2 strip, cols=d1) ----
    f32x4 a3[4];
    #pragma unroll
    for (int i=0;i<4;i++) a3[i]=(f32x4){0.f,0.f,0.f,0.f};
    gemm64(dxA, hA, w, q, col, a3);
    // ---- G4: dh = dx2 @ w2^T ; dx1 = dh*silu'(x1) (rows=token strip, cols=d1) ----
    f32x4 a4[4];
    #pragma unroll
    for (int i=0;i<4;i++) a4[i]=(f32x4){0.f,0.f,0.f,0.f};
    gemm64(dxB, w2b, w, q, col, a4);

    size_t gb = (size_t)bhn*4096;
    #pragma unroll
    for (int nt=0;nt<4;nt++)
        #pragma unroll
        for (int reg=0;reg<4;reg++){
            int d2 = w*16 + q*4 + reg;
            int d1 = nt*16 + col;
            g2T[gb + d2*DD + d1] = f2bf(-a3[nt][reg]);
        }
    #pragma unroll
    for (int nt=0;nt<4;nt++)
        #pragma unroll
        for (int reg=0;reg<4;reg++){
            int idx = nt*4+reg;
            int token = w*16 + q*4 + reg;
            int d1 = nt*16 + col;
            float dsl = sg[idx] + hr[idx]*(1.f-sg[idx]);
            dx1T[d1*LDSP + token] = f2bf(a4[nt][reg]*dsl);
        }
    __syncthreads();

    // ---- G5: g1^T = dx1^T @ kc  (rows=d1 strip, cols=p) ----
    f32x4 a5[4];
    #pragma unroll
    for (int i=0;i<4;i++) a5[i]=(f32x4){0.f,0.f,0.f,0.f};
    gemm64(dx1T, kcT, w, q, col, a5);
    #pragma unroll
    for (int nt=0;nt<4;nt++)
        #pragma unroll
        for (int reg=0;reg<4;reg++){
            int d1 = w*16 + q*4 + reg;
            int p  = nt*16 + col;
            g1T[gb + d1*DD + p] = f2bf(-a5[nt][reg]);
        }
}

// ---------------------------------------------------------------------------
// K5: scans (unchanged — layout-agnostic over the 4096-elem flat dim)
// ---------------------------------------------------------------------------
__global__ __launch_bounds__(256) void k_scan(
    uint16_t* __restrict__ g1, uint16_t* __restrict__ g2,
    const float* __restrict__ mom, const float* __restrict__ dec)
{
    int blk = blockIdx.x;            // [0,512)
    int arr = blk>>8; int rem = blk&255;
    int bh = rem>>3; int eg = rem&7;
    int e2 = eg*512 + threadIdx.x*2;
    uint16_t* gp = arr ? g2 : g1;
    __shared__ float smg[NN], sdc[NN];
    if (threadIdx.x < NN){
        smg[threadIdx.x] = mom[bh*NN+threadIdx.x];
        sdc[threadIdx.x] = 1.f - dec[bh*NN+threadIdx.x];
    }
    __syncthreads();
    size_t base = (size_t)bh*NN*4096 + e2;
    float ma=0.f, mb=0.f, ua=0.f, ub=0.f;
    for (int t=0;t<NN;t++){
        uint32_t w = *(const uint32_t*)&gp[base + (size_t)t*4096];
        float f0 = bf2f(w&0xffffu), f1 = bf2f(w>>16);
        float mg = smg[t], dc = sdc[t];
        ma = fmaf(mg,ma,f0); ua = fmaf(dc,ua,ma);
        mb = fmaf(mg,mb,f1); ub = fmaf(dc,ub,mb);
        *(uint32_t*)&gp[base + (size_t)t*4096] =
            (uint32_t)f2bf(ua) | ((uint32_t)f2bf(ub)<<16);
    }
}

// ---------------------------------------------------------------------------
// K6: retrieve via MFMA. One block per (bh,n), 4 waves.
// u1T/u2T are the scanned updates in TRANSPOSED layout [d_out][d_in] —
// exactly the (w+u)^T rows the B-fragment wants.
// ---------------------------------------------------------------------------
__global__ __launch_bounds__(256) void k_retrieve(
    const uint16_t* __restrict__ qbuf, const uint16_t* __restrict__ u1T,
    const uint16_t* __restrict__ u2T, const float* __restrict__ w1,
    const float* __restrict__ w2, const float* __restrict__ gamma,
    const float* __restrict__ gate_t, uint16_t* __restrict__ y)
{
    __shared__ uint16_t qc[64*LDSP];
    __shared__ uint16_t W1s[64*LDSP];   // (w1+u1)^T rows: [d1][p]
    __shared__ uint16_t W2s[64*LDSP];   // (w2+u2)^T rows: [d2][d1]
    __shared__ uint16_t hB[64*LDSP];    // h rows: [token][d1]
    __shared__ float gate_sh[64], gam_sh[64];
    int bhn = blockIdx.x;
    int bh = bhn>>7, n = bhn&127;
    int b = bh>>3, h = bh&7;
    int tid = threadIdx.x, tx = tid&15, ty = tid>>4;
    int w = tid>>6, lane = tid&63, q = lane>>4, col = lane&15;
    size_t cbase = ((size_t)bh*TT + n*CC)*DD;
    size_t ub = (size_t)bhn*4096;

    #pragma unroll
    for (int r=0;r<4;r++){
        int row = ty*4+r;     // d_out index for W staging; token for qc
        *(ushort4*)&qc[row*LDSP + tx*4] =
            *(const ushort4*)&qbuf[cbase + row*DD + tx*4];
        ushort4 u14 = *(const ushort4*)&u1T[ub + row*DD + tx*4];
        W1s[row*LDSP + tx*4+0] = f2bf(w1[(tx*4+0)*DD + row] + bf2f(u14.x));
        W1s[row*LDSP + tx*4+1] = f2bf(w1[(tx*4+1)*DD + row] + bf2f(u14.y));
        W1s[row*LDSP + tx*4+2] = f2bf(w1[(tx*4+2)*DD + row] + bf2f(u14.z));
        W1s[row*LDSP + tx*4+3] = f2bf(w1[(tx*4+3)*DD + row] + bf2f(u14.w));
        ushort4 u24 = *(const ushort4*)&u2T[ub + row*DD + tx*4];
        W2s[row*LDSP + tx*4+0] = f2bf(w2[(tx*4+0)*DD + row] + bf2f(u24.x));
        W2s[row*LDSP + tx*4+1] = f2bf(w2[(tx*4+1)*DD + row] + bf2f(u24.y));
        W2s[row*LDSP + tx*4+2] = f2bf(w2[(tx*4+2)*DD + row] + bf2f(u24.z));
        W2s[row*LDSP + tx*4+3] = f2bf(w2[(tx*4+3)*DD + row] + bf2f(u24.w));
    }
    if (tid < 64){
        gate_sh[tid] = gate_t[((size_t)b*TT + n*CC + tid)*HH + h];
        gam_sh[tid]  = gamma[h*DD + tid];
    }
    __syncthreads();

    // G1: x1 = qc @ (w1+u1); h = silu
    f32x4 a1[4];
    #pragma unroll
    for (int i=0;i<4;i++) a1[i]=(f32x4){0.f,0.f,0.f,0.f};
    gemm64(qc, W1s, w, q, col, a1);
    #pragma unroll
    for (int nt=0;nt<4;nt++)
        #pragma unroll
        for (int reg=0;reg<4;reg++){
            float x = a1[nt][reg];
            int token = w*16 + q*4 + reg;
            int d1 = nt*16 + col;
            hB[token*LDSP + d1] = f2bf(x*sigmoidf_(x));
        }
    __syncthreads();

    // G2: x = h @ (w2+u2); rmsnorm(d=64) * (1+gamma) * gate -> y
    f32x4 a2[4];
    #pragma unroll
    for (int i=0;i<4;i++) a2[i]=(f32x4){0.f,0.f,0.f,0.f};
    gemm64(hB, W2s, w, q, col, a2);
    #pragma unroll
    for (int reg=0;reg<4;reg++){
        float p = 0.f;
        #pragma unroll
        for (int nt=0;nt<4;nt++) p += a2[nt][reg]*a2[nt][reg];
        p += __shfl_xor(p,1,64);
        p += __shfl_xor(p,2,64);
        p += __shfl_xor(p,4,64);
        p += __shfl_xor(p,8,64);
        float sclv = rsqrtf(p*(1.0f/DD)+EPS);
        int token = w*16 + q*4 + reg;
        float gt = gate_sh[token];
        size_t yb = ((size_t)b*TT + n*CC + token)*DIMM + h*DD;
        #pragma unroll
        for (int nt=0;nt<4;nt++){
            int d2 = nt*16 + col;
            y[yb + d2] = f2bf(a2[nt][reg]*sclv*(1.f+gam_sh[d2])*gt);
        }
    }
}

// ---------------------------------------------------------------------------
// K7: zero pads (unchanged)
// ---------------------------------------------------------------------------
__global__ __launch_bounds__(256) void k_zero(
    uint16_t* __restrict__ qbuf, float* __restrict__ out, float* __restrict__ gate_t)
{
    int g = blockIdx.x*256 + threadIdx.x;
    const int QN = BHH*63*DD;          // 129024
    const int ON = BB*63*DIMM;         // 129024
    const int GN = BB*63*HH;           // 2016
    if (g < QN){
        int bh = g/4032; int r = g - bh*4032;
        int j = 8129 + (r>>6); int dk = r&63;
        qbuf[((size_t)bh*TT + j)*DD + dk] = 0;
    } else if (g < QN+ON){
        int g2i = g - QN;
        int b = g2i/(63*512); int r = g2i - b*63*512;
        int t = r>>9; int e = r&511;
        out[((size_t)b*TT + t)*DIMM + e] = 0.f;
    } else if (g < QN+ON+GN){
        int g3 = g - QN - ON;
        int b = g3/(63*HH); int r = g3 - b*63*HH;
        int j = 8129 + (r>>3); int hh = r&7;
        gate_t[((size_t)b*TT + j)*HH + hh] = 0.f;
    }
}

// ---------------------------------------------------------------------------
extern "C" void kernel_launch(void* const* d_in, const int* in_sizes, int n_in,
                              void* d_out, int out_size, void* d_ws, size_t ws_size,
                              hipStream_t stream)
{
    (void)in_sizes; (void)n_in; (void)out_size; (void)ws_size;
    const float* seq    = (const float*)d_in[0];
    const float* w1     = (const float*)d_in[1];
    const float* w2     = (const float*)d_in[2];
    const float* Wq     = (const float*)d_in[3];
    const float* Wkv    = (const float*)d_in[4];
    const float* Wstep  = (const float*)d_in[5];
    const float* Wmom   = (const float*)d_in[6];
    const float* Wdecay = (const float*)d_in[7];
    const float* Wgate  = (const float*)d_in[8];
    const float* Wcomb  = (const float*)d_in[9];
    const float* gamma  = (const float*)d_in[10];
    float* out = (float*)d_out;

    float* scale = (float*)d_ws;          // 32768
    float* lr_t  = scale + 32768;         // 262144  [b][t][h]
    float* gate_t= lr_t + 262144;         // 262144  [b][j][h]
    float* mom   = gate_t + 262144;       // 4096
    float* dec   = mom + 4096;            // 4096
    uint16_t* btkv = (uint16_t*)(dec + 4096);  // 1024*512 bf16 [n][k]
    uint16_t* btq  = btkv + 1024*512;          // 512*512
    uint16_t* btc  = btq  + 512*512;           // 512*512
    uint16_t* kb = btc + 512*512;            // 16777216 bf16 (q reuses after k_grad)
    uint16_t* vb = kb + 16777216;            // 16777216 bf16 (y reuses after k_retrieve)
    uint16_t* g1 = vb + 16777216;            // 16777216 bf16 g1^T (scan -> upd1^T)
    uint16_t* g2 = g1 + 16777216;            // 16777216 bf16 g2^T (scan -> upd2^T)

    k_transpose<<<dim3(32,16), 256, 0, stream>>>(Wkv,   btkv, 1024);
    k_transpose<<<dim3(16,16), 256, 0, stream>>>(Wq,    btq,  512);
    k_transpose<<<dim3(16,16), 256, 0, stream>>>(Wcomb, btc,  512);
    k_norm_scale <<<8192, 256, 0, stream>>>(seq, Wstep, Wgate, scale, lr_t, gate_t);
    k_chunk_gates<<<BB*NN, 512, 0, stream>>>(seq, scale, Wmom, Wdecay, mom, dec);
    k_gemm_mfma<0><<<dim3(8, 256), 256, 0, stream>>>(seq, btkv, scale, kb, vb);
    k_grad   <<<BHH*NN, 256, 0, stream>>>(kb, vb, lr_t, w1, w2, g1, g2);
    k_scan   <<<512, 256, 0, stream>>>(g1, g2, mom, dec);
    k_gemm_mfma<1><<<dim3(4, 256), 256, 0, stream>>>(seq, btq, scale, kb /*q*/, nullptr);
    k_zero   <<<1017, 256, 0, stream>>>(kb /*q*/, out, gate_t);
    k_retrieve<<<BHH*NN, 256, 0, stream>>>(kb /*q*/, g1, g2, w1, w2, gamma, gate_t, vb /*y*/);
    k_gemm_mfma<2><<<dim3(4, 256), 256, 0, stream>>>(vb /*y*/, btc, nullptr, out, nullptr);
}